// Round 3
// baseline (211.874 us; speedup 1.0000x reference)
//
#include <hip/hip_runtime.h>
#include <hip/hip_bf16.h>

// Problem constants
constexpr int Bc = 2, Sc = 2048, Ec = 1024, Hc = 16, Dc = 64;
constexpr int Mrows = Bc * Sc;   // 4096
constexpr int Kdim  = Ec;        // 1024

typedef float  floatx4 __attribute__((ext_vector_type(4)));
typedef short  shortx8 __attribute__((ext_vector_type(8)));

__device__ inline unsigned short f2bf(float f) {
    union { __hip_bfloat16 h; unsigned short u; } cv;
    cv.h = __float2bfloat16(f);
    return cv.u;
}
__device__ inline float bf2f(unsigned short u) {
    union { unsigned int i; float f; } c; c.i = ((unsigned int)u) << 16; return c.f;
}
__device__ inline float exp2_fast(float x) {
#if __has_builtin(__builtin_amdgcn_exp2f)
    return __builtin_amdgcn_exp2f(x);
#else
    return __expf(x * 0.69314718056f);
#endif
}

// pack two f32 -> one dword of 2x bf16 (lo->[15:0], hi->[31:16])
// HW-verified gfx950 asm (learn_hip m214v22 / m240 — no builtin exists).
__device__ __forceinline__ unsigned cvtpk_bf16(float lo, float hi) {
    unsigned r;
    asm("v_cvt_pk_bf16_f32 %0, %1, %2" : "=v"(r) : "v"(lo), "v"(hi));
    return r;
}

// Emulated register-pair half-swaps via __shfl_xor (ds_bpermute, permutation
// pattern -> conflict-free).  Semantics identical to v_permlane32_swap_b32 /
// v_permlane16_swap_b32:
//   swap32: a[32:63] <-> b[0:31]
//   swap16: a[16:31]<->b[0:15], a[48:63]<->b[32:47]
__device__ __forceinline__ void swap32(unsigned& a, unsigned& b, int lane) {
    unsigned a2 = __shfl_xor(a, 32, 64);
    unsigned b2 = __shfl_xor(b, 32, 64);
    const bool lo = (lane & 32) == 0;
    unsigned na = lo ? a : b2;
    unsigned nb = lo ? a2 : b;
    a = na; b = nb;
}
__device__ __forceinline__ void swap16(unsigned& a, unsigned& b, int lane) {
    unsigned a2 = __shfl_xor(a, 16, 64);
    unsigned b2 = __shfl_xor(b, 16, 64);
    const bool lo = (lane & 16) == 0;
    unsigned na = lo ? a : b2;
    unsigned nb = lo ? a2 : b;
    a = na; b = nb;
}

// async global->LDS DMA, 16 B/lane; HW dest = wave-uniform base + lane*16.
__device__ __forceinline__ void gll16(const void* g, void* lds) {
    __builtin_amdgcn_global_load_lds(
        (const __attribute__((address_space(1))) void*)g,
        (__attribute__((address_space(3))) void*)lds, 16, 0, 0);
}

// ---------------------------------------------------------------------------
// Kernel 0: convert x, Wq, Wk, Wv, Wc (fp32) -> bf16 workspace
// ---------------------------------------------------------------------------
__global__ __launch_bounds__(256) void convert_all_kernel(
    const float* __restrict__ x,  const float* __restrict__ Wq,
    const float* __restrict__ Wk, const float* __restrict__ Wv,
    const float* __restrict__ Wc,
    unsigned short* __restrict__ xb,  unsigned short* __restrict__ Wqb,
    unsigned short* __restrict__ Wkb, unsigned short* __restrict__ Wvb,
    unsigned short* __restrict__ Wcb)
{
    const long t = (long)blockIdx.x * 256 + threadIdx.x;
    const long i = t * 4;
    const float* src; unsigned short* dst; long off;
    if (i < 4194304) { src = x; dst = xb; off = i; }
    else {
        long j = i - 4194304;
        int wsel = (int)(j >> 20);
        off = j & 1048575;
        src = (wsel == 0) ? Wq : (wsel == 1) ? Wk : (wsel == 2) ? Wv : Wc;
        dst = (wsel == 0) ? Wqb : (wsel == 1) ? Wkb : (wsel == 2) ? Wvb : Wcb;
    }
    float4 v = *(const float4*)(src + off);
    unsigned short tmp[4] __attribute__((aligned(8)));
    tmp[0] = f2bf(v.x); tmp[1] = f2bf(v.y); tmp[2] = f2bf(v.z); tmp[3] = f2bf(v.w);
    *(uint2*)(dst + off) = *(uint2*)tmp;
}

// ---------------------------------------------------------------------------
// Kernel 1: MFMA projection + quantum epilogue, 128x128 tile, async staging.
// Tiles are UNPADDED (row stride 128 B); global reads are chunk-swizzled
// (cg = c ^ (row&7)) so b128 fragment reads spread uniformly over banks.
// blockIdx.z selects {q,k,v}; z==2 writes V transposed [B,H,D,S].
// ---------------------------------------------------------------------------
__global__ __launch_bounds__(256) void proj_mfma_kernel(
    const unsigned short* __restrict__ Ab,   // x bf16 [4096,1024]
    const unsigned short* __restrict__ Wqb,
    const unsigned short* __restrict__ Wkb,
    const unsigned short* __restrict__ Wvb,
    unsigned short* __restrict__ oq,         // [B,H,S,D]
    unsigned short* __restrict__ ok,         // [B,H,S,D]
    unsigned short* __restrict__ ov)         // [B,H,D,S]
{
    __shared__ __align__(16) char smem[33792];   // As 16K | Ws 16K; Cs overlay 33792
    float (*Cs)[132] = (float(*)[132])smem;
    __shared__ float Sp[64][9];

    const int z = blockIdx.z;
    const unsigned short* Wb = (z == 0) ? Wqb : (z == 1) ? Wkb : Wvb;
    unsigned short* out      = (z == 0) ? oq  : (z == 1) ? ok  : ov;
    const int mode = (z == 2) ? 1 : 0;

    const int tid = threadIdx.x;
    const int lane = tid & 63;
    const int w = tid >> 6, l15 = tid & 15, quad = (tid >> 4) & 3;
    const int wq = w >> 1, wn = w & 1;
    const int m0 = blockIdx.x * 128;
    const int n0 = blockIdx.y * 128;
    const int h0 = n0 >> 6;
    const int sw = l15 & 7;

    floatx4 acc[4][4];
    #pragma unroll
    for (int ms = 0; ms < 4; ++ms)
        #pragma unroll
        for (int ns = 0; ns < 4; ++ns)
            #pragma unroll
            for (int e = 0; e < 4; ++e) acc[ms][ns][e] = 0.0f;

    for (int k0 = 0; k0 < Kdim; k0 += 64) {
        #pragma unroll
        for (int j = 0; j < 4; ++j) {
            int idx = j * 64 + lane;
            int row = 32 * w + (idx >> 3);
            int cg  = ((idx & 7) ^ (idx >> 3)) & 7;
            gll16(Ab + (size_t)(m0 + row) * Kdim + k0 + cg * 8,
                  smem + 4096 * w + 1024 * j);
            gll16(Wb + (size_t)(n0 + row) * Kdim + k0 + cg * 8,
                  smem + 16384 + 4096 * w + 1024 * j);
        }
        __syncthreads();
        #pragma unroll
        for (int ks = 0; ks < 2; ++ks) {
            shortx8 af[4], bf[4];
            #pragma unroll
            for (int ms = 0; ms < 4; ++ms)
                af[ms] = *(shortx8*)(smem + (64 * wq + 16 * ms + l15) * 128
                                     + (((4 * ks + quad) ^ sw) << 4));
            #pragma unroll
            for (int ns = 0; ns < 4; ++ns)
                bf[ns] = *(shortx8*)(smem + 16384 + (64 * wn + 16 * ns + l15) * 128
                                     + (((4 * ks + quad) ^ sw) << 4));
            #pragma unroll
            for (int ms = 0; ms < 4; ++ms)
                #pragma unroll
                for (int ns = 0; ns < 4; ++ns)
                    acc[ms][ns] = __builtin_amdgcn_mfma_f32_16x16x32_bf16(
                        af[ms], bf[ns], acc[ms][ns], 0, 0, 0);
        }
        __syncthreads();
    }

    const int b = m0 >> 11;
    const int sbase = m0 & (Sc - 1);

    // Epilogue: two 64-row passes (Cs overlays staging LDS; K-loop done)
    for (int pass = 0; pass < 2; ++pass) {
        if (wq == pass) {
            #pragma unroll
            for (int ms = 0; ms < 4; ++ms)
                #pragma unroll
                for (int ns = 0; ns < 4; ++ns)
                    #pragma unroll
                    for (int r = 0; r < 4; ++r)
                        Cs[16 * ms + 4 * quad + r][64 * wn + 16 * ns + l15] =
                            __cosf(acc[ms][ns][r]);
        }
        __syncthreads();
        #pragma unroll
        for (int t = tid; t < 512; t += 256) {
            int row = t >> 3, seg = t & 7;
            float pr = 1.0f;
            #pragma unroll
            for (int c = 0; c < 16; ++c) pr *= Cs[row][seg * 16 + c];
            Sp[row][seg] = pr;
        }
        __syncthreads();
        if (mode == 0) {
            #pragma unroll
            for (int t = tid; t < 512; t += 256) {
                int row = t >> 3, seg = t & 7;
                float p = 1.0f;
                for (int j = (seg & 4); j < seg; ++j) p *= Sp[row][j];
                unsigned short tmp[16] __attribute__((aligned(16)));
                #pragma unroll
                for (int c = 0; c < 16; ++c) { p *= Cs[row][seg * 16 + c]; tmp[c] = f2bf(p); }
                int h = h0 + (seg >> 2);
                int s = sbase + pass * 64 + row;
                size_t base = (((size_t)b * Hc + h) * Sc + s) * Dc + (seg & 3) * 16;
                *(shortx8*)(out + base)     = *(shortx8*)&tmp[0];
                *(shortx8*)(out + base + 8) = *(shortx8*)&tmp[8];
            }
            __syncthreads();
        } else {
            #pragma unroll
            for (int t = tid; t < 512; t += 256) {
                int row = t >> 3, seg = t & 7;
                float p = 1.0f;
                for (int j = (seg & 4); j < seg; ++j) p *= Sp[row][j];
                #pragma unroll
                for (int c = 0; c < 16; ++c) { p *= Cs[row][seg * 16 + c]; Cs[row][seg * 16 + c] = p; }
            }
            __syncthreads();
            #pragma unroll
            for (int t = tid; t < 512; t += 256) {
                int col = t >> 2, chunk = t & 3;
                int h = h0 + (col >> 6), d = col & 63;
                unsigned short tmp[16] __attribute__((aligned(16)));
                #pragma unroll
                for (int j = 0; j < 16; ++j) tmp[j] = f2bf(Cs[chunk * 16 + j][col]);
                size_t base = (((size_t)b * Hc + h) * Dc + d) * Sc
                              + sbase + pass * 64 + chunk * 16;
                *(shortx8*)(out + base)     = *(shortx8*)&tmp[0];
                *(shortx8*)(out + base + 8) = *(shortx8*)&tmp[8];
            }
            __syncthreads();
        }
    }
}

// ---------------------------------------------------------------------------
// Kernel 2: MFMA flash attention, QTILE=128, fixed-max softmax, S-SPLIT x2.
// v3: P never touches LDS. QK^T output (lane holds P[16mt+4quad+r][l15]) is
// repacked to the PV B-operand layout (lane needs P[32ks+8quad+j][l15]) fully
// in-register: cvt_pk_bf16 pairs + swap32 + swap16 (shfl_xor emulation of the
// permlane pair-swaps; verified lane-by-lane against the MFMA B layout):
//   a=pk(p[2ks][0],p[2ks][1]), b=pk(p[2ks+1][0],p[2ks+1][1])
//   swap32(a,b); swap16(a,b)  ->  a = pf.x[0], b = pf.x[2]  (pw pair -> x[1],x[3])
// This frees the 18K Pq buffer -> K/V double-buffered (2x16K), one barrier
// per K-tile: stage(kt+1) issues after the barrier and flies under compute(kt).
// ---------------------------------------------------------------------------
__global__ __launch_bounds__(256) void attn_mfma_kernel(
    const unsigned short* __restrict__ qg,   // [B,H,S,D]
    const unsigned short* __restrict__ kg,   // [B,H,S,D]
    const unsigned short* __restrict__ vtg,  // [B,H,D,S]
    unsigned short* __restrict__ o1,         // partial O, half 0 [B,S,E]
    unsigned short* __restrict__ o2,         // partial O, half 1 [B,S,E]
    float* __restrict__ lpart)               // [2][B*H][S]
{
    __shared__ __align__(16) char smem[32768];   // buf0: Ks 8K|VTs 8K, buf1: same

    const int tid  = threadIdx.x;
    const int lane = tid & 63;
    const int w    = tid >> 6;
    const int l15  = tid & 15;
    const int quad = (tid >> 4) & 3;
    const int qb   = blockIdx.x;
    const int half = blockIdx.y;
    const int bh   = blockIdx.z;
    const int sw   = l15 & 7;

    const unsigned short* qp = qg  + (size_t)bh * Sc * Dc;
    const unsigned short* kp = kg  + (size_t)bh * Sc * Dc;
    const unsigned short* vp = vtg + (size_t)bh * Dc * Sc;

    int qrow[2];
    shortx8 qf[2][2];
    #pragma unroll
    for (int qs = 0; qs < 2; ++qs) {
        qrow[qs] = qb * 128 + 32 * w + 16 * qs + l15;
        qf[qs][0] = *(const shortx8*)(qp + (size_t)qrow[qs] * Dc + 8 * quad);
        qf[qs][1] = *(const shortx8*)(qp + (size_t)qrow[qs] * Dc + 32 + 8 * quad);
    }

    floatx4 Oacc[2][4];
    #pragma unroll
    for (int qs = 0; qs < 2; ++qs)
        #pragma unroll
        for (int mt = 0; mt < 4; ++mt)
            #pragma unroll
            for (int e = 0; e < 4; ++e) Oacc[qs][mt][e] = 0.0f;
    float lsum[2] = {0.0f, 0.0f};

    const float cexp = 0.125f * 1.442695041f;   // score scale * log2(e)

    // async stage of one 64-row K tile + matching V^T tile into buffer `buf`
    auto stage = [&](int kt, int buf) {
        #pragma unroll
        for (int j = 0; j < 2; ++j) {
            int idx = j * 64 + lane;
            int row = 16 * w + (idx >> 3);
            int cg  = ((idx & 7) ^ (idx >> 3)) & 7;
            gll16(kp + (size_t)(kt * 64 + row) * Dc + cg * 8,
                  smem + (buf << 14) + 2048 * w + 1024 * j);
            gll16(vp + (size_t)row * Sc + kt * 64 + cg * 8,
                  smem + (buf << 14) + 8192 + 2048 * w + 1024 * j);
        }
    };

    int cur = 0;
    stage(half * 16, 0);

    for (int it = 0; it < 16; ++it) {
        const int kt = half * 16 + it;
        // barrier drains this thread's vmcnt (stage(kt) landed) and guarantees
        // all waves finished reading buf cur^1 (tile kt-1) -> safe to overwrite.
        __syncthreads();
        if (it < 15) stage(kt + 1, cur ^ 1);

        const char* kb = smem + (cur << 14);

        // --- QK^T phase: K fragments + MFMA + exp + pack (kf dead after) ---
        shortx8 kf[2][4];
        #pragma unroll
        for (int ks = 0; ks < 2; ++ks)
            #pragma unroll
            for (int mt = 0; mt < 4; ++mt)
                kf[ks][mt] = *(shortx8*)(kb + (16 * mt + l15) * 128
                                         + (((4 * ks + quad) ^ sw) << 4));

        unsigned pu[2][4], pw[2][4];
        #pragma unroll
        for (int qs = 0; qs < 2; ++qs) {
            floatx4 st[4];
            #pragma unroll
            for (int mt = 0; mt < 4; ++mt)
                #pragma unroll
                for (int e = 0; e < 4; ++e) st[mt][e] = 0.0f;
            #pragma unroll
            for (int ks = 0; ks < 2; ++ks)
                #pragma unroll
                for (int mt = 0; mt < 4; ++mt)
                    st[mt] = __builtin_amdgcn_mfma_f32_16x16x32_bf16(
                        kf[ks][mt], qf[qs][ks], st[mt], 0, 0, 0);

            float rs = 0.0f;
            #pragma unroll
            for (int mt = 0; mt < 4; ++mt) {
                float p0 = exp2_fast(st[mt][0] * cexp);
                float p1 = exp2_fast(st[mt][1] * cexp);
                float p2 = exp2_fast(st[mt][2] * cexp);
                float p3 = exp2_fast(st[mt][3] * cexp);
                rs += (p0 + p1) + (p2 + p3);
                pu[qs][mt] = cvtpk_bf16(p0, p1);
                pw[qs][mt] = cvtpk_bf16(p2, p3);
            }
            lsum[qs] += rs;
        }

        // --- PV phase: V fragments + in-register repack + MFMA ---
        shortx8 vf[2][4];
        #pragma unroll
        for (int ks = 0; ks < 2; ++ks)
            #pragma unroll
            for (int mt = 0; mt < 4; ++mt)
                vf[ks][mt] = *(shortx8*)(kb + 8192 + (16 * mt + l15) * 128
                                         + (((4 * ks + quad) ^ sw) << 4));

        #pragma unroll
        for (int qs = 0; qs < 2; ++qs)
            #pragma unroll
            for (int ks = 0; ks < 2; ++ks) {
                unsigned a = pu[qs][2 * ks], b = pu[qs][2 * ks + 1];
                unsigned c = pw[qs][2 * ks], d = pw[qs][2 * ks + 1];
                swap32(a, b, lane); swap16(a, b, lane);
                swap32(c, d, lane); swap16(c, d, lane);
                union { unsigned x[4]; shortx8 s; } pf;
                pf.x[0] = a; pf.x[1] = c; pf.x[2] = b; pf.x[3] = d;
                #pragma unroll
                for (int mt = 0; mt < 4; ++mt)
                    Oacc[qs][mt] = __builtin_amdgcn_mfma_f32_16x16x32_bf16(
                        vf[ks][mt], pf.s, Oacc[qs][mt], 0, 0, 0);
            }

        cur ^= 1;
    }

    // store partial O (bf16, unnormalized) + partial l (fp32)
    const int b = bh >> 4, hh = bh & 15;
    unsigned short* opart = half ? o2 : o1;
    float* lp = lpart + ((size_t)half * (Bc * Hc) + bh) * Sc;
    #pragma unroll
    for (int qs = 0; qs < 2; ++qs) {
        float l = lsum[qs];
        l += __shfl_xor(l, 16, 64);
        l += __shfl_xor(l, 32, 64);
        if (quad == 0) lp[qrow[qs]] = l;
        #pragma unroll
        for (int mt = 0; mt < 4; ++mt) {
            unsigned short tmp[4] __attribute__((aligned(8)));
            #pragma unroll
            for (int r = 0; r < 4; ++r) tmp[r] = f2bf(Oacc[qs][mt][r]);
            size_t base = ((size_t)b * Sc + qrow[qs]) * Ec + hh * 64 + 16 * mt + 4 * quad;
            *(uint2*)(opart + base) = *(uint2*)tmp;
        }
    }
}

// ---------------------------------------------------------------------------
// Kernel 2b: combine halves: att = (O1 + O2) / (l1 + l2), in place into o1.
// ---------------------------------------------------------------------------
__global__ __launch_bounds__(256) void combine_kernel(
    unsigned short* __restrict__ o1,         // in/out (becomes att)
    const unsigned short* __restrict__ o2,
    const float* __restrict__ lpart)         // [2][B*H][S]
{
    const size_t t = (size_t)blockIdx.x * 256 + threadIdx.x;
    const size_t base = t * 8;
    const int e = (int)(base & (Ec - 1));
    const int h = e >> 6;
    const size_t bs = base >> 10;
    const int b = (int)(bs >> 11), s = (int)(bs & (Sc - 1));
    const int bh = b * Hc + h;
    const float l = lpart[(size_t)bh * Sc + s]
                  + lpart[(size_t)(Bc * Hc + bh) * Sc + s];
    const float inv = 1.0f / l;
    uint4 a = *(const uint4*)(o1 + base);
    uint4 c = *(const uint4*)(o2 + base);
    const unsigned short* ua = (const unsigned short*)&a;
    const unsigned short* uc = (const unsigned short*)&c;
    unsigned short r[8] __attribute__((aligned(16)));
    #pragma unroll
    for (int i = 0; i < 8; ++i)
        r[i] = f2bf((bf2f(ua[i]) + bf2f(uc[i])) * inv);
    *(uint4*)(o1 + base) = *(uint4*)r;
}

// ---------------------------------------------------------------------------
// Kernel 3: MFMA out-projection, 64x128 tile, async swizzled staging.
// ---------------------------------------------------------------------------
__global__ __launch_bounds__(256) void outproj_mfma_kernel(
    const unsigned short* __restrict__ Ab,   // attb [4096,1024]
    const unsigned short* __restrict__ Wb,   // Wcb [1024,1024]
    const float* __restrict__ bias,
    float* __restrict__ out)                 // [4096,1024] fp32
{
    __shared__ __align__(16) char smem[24576];   // As 8K | Ws 16K

    const int tid = threadIdx.x;
    const int lane = tid & 63;
    const int w = tid >> 6, l15 = tid & 15, quad = (tid >> 4) & 3;
    const int wq = w >> 1, wn = w & 1;
    const int m0 = blockIdx.x * 64;
    const int n0 = blockIdx.y * 128;
    const int sw = l15 & 7;

    floatx4 acc[2][4];
    #pragma unroll
    for (int ms = 0; ms < 2; ++ms)
        #pragma unroll
        for (int ns = 0; ns < 4; ++ns)
            #pragma unroll
            for (int e = 0; e < 4; ++e) acc[ms][ns][e] = 0.0f;

    for (int k0 = 0; k0 < Kdim; k0 += 64) {
        #pragma unroll
        for (int j = 0; j < 2; ++j) {
            int idx = j * 64 + lane;
            int row = 16 * w + (idx >> 3);
            int cg  = ((idx & 7) ^ (idx >> 3)) & 7;
            gll16(Ab + (size_t)(m0 + row) * Kdim + k0 + cg * 8,
                  smem + 2048 * w + 1024 * j);
        }
        #pragma unroll
        for (int j = 0; j < 4; ++j) {
            int idx = j * 64 + lane;
            int row = 32 * w + (idx >> 3);
            int cg  = ((idx & 7) ^ (idx >> 3)) & 7;
            gll16(Wb + (size_t)(n0 + row) * Kdim + k0 + cg * 8,
                  smem + 8192 + 4096 * w + 1024 * j);
        }
        __syncthreads();
        #pragma unroll
        for (int ks = 0; ks < 2; ++ks) {
            shortx8 af[2], bf[4];
            #pragma unroll
            for (int ms = 0; ms < 2; ++ms)
                af[ms] = *(shortx8*)(smem + (32 * wq + 16 * ms + l15) * 128
                                     + (((4 * ks + quad) ^ sw) << 4));
            #pragma unroll
            for (int ns = 0; ns < 4; ++ns)
                bf[ns] = *(shortx8*)(smem + 8192 + (64 * wn + 16 * ns + l15) * 128
                                     + (((4 * ks + quad) ^ sw) << 4));
            #pragma unroll
            for (int ms = 0; ms < 2; ++ms)
                #pragma unroll
                for (int ns = 0; ns < 4; ++ns)
                    acc[ms][ns] = __builtin_amdgcn_mfma_f32_16x16x32_bf16(
                        af[ms], bf[ns], acc[ms][ns], 0, 0, 0);
        }
        __syncthreads();
    }

    #pragma unroll
    for (int ns = 0; ns < 4; ++ns) {
        const float bv = bias[n0 + 64 * wn + 16 * ns + l15];
        #pragma unroll
        for (int ms = 0; ms < 2; ++ms)
            #pragma unroll
            for (int r = 0; r < 4; ++r) {
                int m = m0 + 32 * wq + 16 * ms + 4 * quad + r;
                out[(size_t)m * Kdim + n0 + 64 * wn + 16 * ns + l15] = acc[ms][ns][r] + bv;
            }
    }
}

// ---------------------------------------------------------------------------
extern "C" void kernel_launch(void* const* d_in, const int* in_sizes, int n_in,
                              void* d_out, int out_size, void* d_ws, size_t ws_size,
                              hipStream_t stream) {
    const float* x  = (const float*)d_in[0];
    const float* Wq = (const float*)d_in[1];
    const float* Wk = (const float*)d_in[2];
    const float* Wv = (const float*)d_in[3];
    const float* Wc = (const float*)d_in[4];
    const float* bc = (const float*)d_in[5];
    float* out = (float*)d_out;

    // ws layout (48 MB): xb 8M | Wqb/Wkb/Wvb/Wcb 2M ea | qb 8M | kb 8M | vtb 8M
    // | attb 8M.  After proj, xb region is reused as O2 partial and Wqb region
    // as lpart (both dead); attb region doubles as O1 partial (combined in place).
    char* p = (char*)d_ws;
    unsigned short* xb   = (unsigned short*)(p);
    unsigned short* Wqb  = (unsigned short*)(p + (8u << 20));
    unsigned short* Wkb  = (unsigned short*)(p + (10u << 20));
    unsigned short* Wvb  = (unsigned short*)(p + (12u << 20));
    unsigned short* Wcb  = (unsigned short*)(p + (14u << 20));
    unsigned short* qb_  = (unsigned short*)(p + (16u << 20));
    unsigned short* kb_  = (unsigned short*)(p + (24u << 20));
    unsigned short* vtb  = (unsigned short*)(p + (32u << 20));
    unsigned short* attb = (unsigned short*)(p + (40u << 20));
    unsigned short* o2b  = xb;                    // dead after proj
    float*          lpart = (float*)(p + (8u << 20));   // dead Wqb region

    hipLaunchKernelGGL(convert_all_kernel, dim3(8192), dim3(256), 0, stream,
                       x, Wq, Wk, Wv, Wc, xb, Wqb, Wkb, Wvb, Wcb);

    hipLaunchKernelGGL(proj_mfma_kernel, dim3(Mrows / 128, Ec / 128, 3), dim3(256), 0, stream,
                       xb, Wqb, Wkb, Wvb, qb_, kb_, vtb);

    hipLaunchKernelGGL(attn_mfma_kernel, dim3(Sc / 128, 2, Bc * Hc), dim3(256), 0, stream,
                       qb_, kb_, vtb, attb, o2b, lpart);

    hipLaunchKernelGGL(combine_kernel, dim3(Mrows * Ec / (256 * 8)), dim3(256), 0, stream,
                       attb, o2b, lpart);

    hipLaunchKernelGGL(outproj_mfma_kernel, dim3(Mrows / 64, Ec / 128), dim3(256), 0, stream,
                       attb, Wcb, bc, out);
}

// Round 4
// 193.788 us; speedup vs baseline: 1.0933x; 1.0933x over previous
//
#include <hip/hip_runtime.h>
#include <hip/hip_bf16.h>

// Problem constants
constexpr int Bc = 2, Sc = 2048, Ec = 1024, Hc = 16, Dc = 64;
constexpr int Mrows = Bc * Sc;   // 4096
constexpr int Kdim  = Ec;        // 1024

typedef float  floatx4 __attribute__((ext_vector_type(4)));
typedef short  shortx8 __attribute__((ext_vector_type(8)));
typedef unsigned uintx2 __attribute__((ext_vector_type(2)));

__device__ inline unsigned short f2bf(float f) {
    union { __hip_bfloat16 h; unsigned short u; } cv;
    cv.h = __float2bfloat16(f);
    return cv.u;
}
__device__ inline float bf2f(unsigned short u) {
    union { unsigned int i; float f; } c; c.i = ((unsigned int)u) << 16; return c.f;
}
__device__ inline float exp2_fast(float x) {
#if __has_builtin(__builtin_amdgcn_exp2f)
    return __builtin_amdgcn_exp2f(x);
#else
    return __expf(x * 0.69314718056f);
#endif
}

// pack two f32 -> one dword of 2x bf16 (lo->[15:0], hi->[31:16])
// HW-verified gfx950 asm (learn_hip m214v22 / m240 — no builtin exists).
__device__ __forceinline__ unsigned cvtpk_bf16(float lo, float hi) {
    unsigned r;
    asm("v_cvt_pk_bf16_f32 %0, %1, %2" : "=v"(r) : "v"(lo), "v"(hi));
    return r;
}

// Register-pair half-swaps.  Semantics:
//   swap32: a[32:63] <-> b[0:31]
//   swap16: a[16:31]<->b[0:15], a[48:63]<->b[32:47]
// Primary: gfx950 v_permlane{32,16}_swap_b32 via builtin (VALU pipe — keeps
// the repack OFF the LDS pipe).  Fallback: __shfl_xor emulation (ds_bpermute,
// LDS pipe) — identical lane mapping, HW-verified in round 3.
#if __has_builtin(__builtin_amdgcn_permlane32_swap)
__device__ __forceinline__ void swap32(unsigned& a, unsigned& b, int) {
    uintx2 r = __builtin_amdgcn_permlane32_swap(a, b, false, false);
    a = r[0]; b = r[1];
}
#else
__device__ __forceinline__ void swap32(unsigned& a, unsigned& b, int lane) {
    unsigned a2 = __shfl_xor(a, 32, 64);
    unsigned b2 = __shfl_xor(b, 32, 64);
    const bool lo = (lane & 32) == 0;
    unsigned na = lo ? a : b2;
    unsigned nb = lo ? a2 : b;
    a = na; b = nb;
}
#endif
#if __has_builtin(__builtin_amdgcn_permlane16_swap)
__device__ __forceinline__ void swap16(unsigned& a, unsigned& b, int) {
    uintx2 r = __builtin_amdgcn_permlane16_swap(a, b, false, false);
    a = r[0]; b = r[1];
}
#else
__device__ __forceinline__ void swap16(unsigned& a, unsigned& b, int lane) {
    unsigned a2 = __shfl_xor(a, 16, 64);
    unsigned b2 = __shfl_xor(b, 16, 64);
    const bool lo = (lane & 16) == 0;
    unsigned na = lo ? a : b2;
    unsigned nb = lo ? a2 : b;
    a = na; b = nb;
}
#endif

// async global->LDS DMA, 16 B/lane; HW dest = wave-uniform base + lane*16.
__device__ __forceinline__ void gll16(const void* g, void* lds) {
    __builtin_amdgcn_global_load_lds(
        (const __attribute__((address_space(1))) void*)g,
        (__attribute__((address_space(3))) void*)lds, 16, 0, 0);
}

// ---------------------------------------------------------------------------
// Kernel 0: convert x, Wq, Wk, Wv, Wc (fp32) -> bf16 workspace
// ---------------------------------------------------------------------------
__global__ __launch_bounds__(256) void convert_all_kernel(
    const float* __restrict__ x,  const float* __restrict__ Wq,
    const float* __restrict__ Wk, const float* __restrict__ Wv,
    const float* __restrict__ Wc,
    unsigned short* __restrict__ xb,  unsigned short* __restrict__ Wqb,
    unsigned short* __restrict__ Wkb, unsigned short* __restrict__ Wvb,
    unsigned short* __restrict__ Wcb)
{
    const long t = (long)blockIdx.x * 256 + threadIdx.x;
    const long i = t * 4;
    const float* src; unsigned short* dst; long off;
    if (i < 4194304) { src = x; dst = xb; off = i; }
    else {
        long j = i - 4194304;
        int wsel = (int)(j >> 20);
        off = j & 1048575;
        src = (wsel == 0) ? Wq : (wsel == 1) ? Wk : (wsel == 2) ? Wv : Wc;
        dst = (wsel == 0) ? Wqb : (wsel == 1) ? Wkb : (wsel == 2) ? Wvb : Wcb;
    }
    float4 v = *(const float4*)(src + off);
    unsigned short tmp[4] __attribute__((aligned(8)));
    tmp[0] = f2bf(v.x); tmp[1] = f2bf(v.y); tmp[2] = f2bf(v.z); tmp[3] = f2bf(v.w);
    *(uint2*)(dst + off) = *(uint2*)tmp;
}

// ---------------------------------------------------------------------------
// Kernel 1: MFMA projection + quantum epilogue, 128x128 tile, async staging.
// Tiles are UNPADDED (row stride 128 B); global reads are chunk-swizzled
// (cg = c ^ (row&7)) so b128 fragment reads spread uniformly over banks.
// blockIdx.z selects {q,k,v}; z==2 writes V transposed [B,H,D,S].
// ---------------------------------------------------------------------------
__global__ __launch_bounds__(256) void proj_mfma_kernel(
    const unsigned short* __restrict__ Ab,   // x bf16 [4096,1024]
    const unsigned short* __restrict__ Wqb,
    const unsigned short* __restrict__ Wkb,
    const unsigned short* __restrict__ Wvb,
    unsigned short* __restrict__ oq,         // [B,H,S,D]
    unsigned short* __restrict__ ok,         // [B,H,S,D]
    unsigned short* __restrict__ ov)         // [B,H,D,S]
{
    __shared__ __align__(16) char smem[33792];   // As 16K | Ws 16K; Cs overlay 33792
    float (*Cs)[132] = (float(*)[132])smem;
    __shared__ float Sp[64][9];

    const int z = blockIdx.z;
    const unsigned short* Wb = (z == 0) ? Wqb : (z == 1) ? Wkb : Wvb;
    unsigned short* out      = (z == 0) ? oq  : (z == 1) ? ok  : ov;
    const int mode = (z == 2) ? 1 : 0;

    const int tid = threadIdx.x;
    const int lane = tid & 63;
    const int w = tid >> 6, l15 = tid & 15, quad = (tid >> 4) & 3;
    const int wq = w >> 1, wn = w & 1;
    const int m0 = blockIdx.x * 128;
    const int n0 = blockIdx.y * 128;
    const int h0 = n0 >> 6;
    const int sw = l15 & 7;

    floatx4 acc[4][4];
    #pragma unroll
    for (int ms = 0; ms < 4; ++ms)
        #pragma unroll
        for (int ns = 0; ns < 4; ++ns)
            #pragma unroll
            for (int e = 0; e < 4; ++e) acc[ms][ns][e] = 0.0f;

    for (int k0 = 0; k0 < Kdim; k0 += 64) {
        #pragma unroll
        for (int j = 0; j < 4; ++j) {
            int idx = j * 64 + lane;
            int row = 32 * w + (idx >> 3);
            int cg  = ((idx & 7) ^ (idx >> 3)) & 7;
            gll16(Ab + (size_t)(m0 + row) * Kdim + k0 + cg * 8,
                  smem + 4096 * w + 1024 * j);
            gll16(Wb + (size_t)(n0 + row) * Kdim + k0 + cg * 8,
                  smem + 16384 + 4096 * w + 1024 * j);
        }
        __syncthreads();
        #pragma unroll
        for (int ks = 0; ks < 2; ++ks) {
            shortx8 af[4], bf[4];
            #pragma unroll
            for (int ms = 0; ms < 4; ++ms)
                af[ms] = *(shortx8*)(smem + (64 * wq + 16 * ms + l15) * 128
                                     + (((4 * ks + quad) ^ sw) << 4));
            #pragma unroll
            for (int ns = 0; ns < 4; ++ns)
                bf[ns] = *(shortx8*)(smem + 16384 + (64 * wn + 16 * ns + l15) * 128
                                     + (((4 * ks + quad) ^ sw) << 4));
            #pragma unroll
            for (int ms = 0; ms < 4; ++ms)
                #pragma unroll
                for (int ns = 0; ns < 4; ++ns)
                    acc[ms][ns] = __builtin_amdgcn_mfma_f32_16x16x32_bf16(
                        af[ms], bf[ns], acc[ms][ns], 0, 0, 0);
        }
        __syncthreads();
    }

    const int b = m0 >> 11;
    const int sbase = m0 & (Sc - 1);

    // Epilogue: two 64-row passes (Cs overlays staging LDS; K-loop done)
    for (int pass = 0; pass < 2; ++pass) {
        if (wq == pass) {
            #pragma unroll
            for (int ms = 0; ms < 4; ++ms)
                #pragma unroll
                for (int ns = 0; ns < 4; ++ns)
                    #pragma unroll
                    for (int r = 0; r < 4; ++r)
                        Cs[16 * ms + 4 * quad + r][64 * wn + 16 * ns + l15] =
                            __cosf(acc[ms][ns][r]);
        }
        __syncthreads();
        #pragma unroll
        for (int t = tid; t < 512; t += 256) {
            int row = t >> 3, seg = t & 7;
            float pr = 1.0f;
            #pragma unroll
            for (int c = 0; c < 16; ++c) pr *= Cs[row][seg * 16 + c];
            Sp[row][seg] = pr;
        }
        __syncthreads();
        if (mode == 0) {
            #pragma unroll
            for (int t = tid; t < 512; t += 256) {
                int row = t >> 3, seg = t & 7;
                float p = 1.0f;
                for (int j = (seg & 4); j < seg; ++j) p *= Sp[row][j];
                unsigned short tmp[16] __attribute__((aligned(16)));
                #pragma unroll
                for (int c = 0; c < 16; ++c) { p *= Cs[row][seg * 16 + c]; tmp[c] = f2bf(p); }
                int h = h0 + (seg >> 2);
                int s = sbase + pass * 64 + row;
                size_t base = (((size_t)b * Hc + h) * Sc + s) * Dc + (seg & 3) * 16;
                *(shortx8*)(out + base)     = *(shortx8*)&tmp[0];
                *(shortx8*)(out + base + 8) = *(shortx8*)&tmp[8];
            }
            __syncthreads();
        } else {
            #pragma unroll
            for (int t = tid; t < 512; t += 256) {
                int row = t >> 3, seg = t & 7;
                float p = 1.0f;
                for (int j = (seg & 4); j < seg; ++j) p *= Sp[row][j];
                #pragma unroll
                for (int c = 0; c < 16; ++c) { p *= Cs[row][seg * 16 + c]; Cs[row][seg * 16 + c] = p; }
            }
            __syncthreads();
            #pragma unroll
            for (int t = tid; t < 512; t += 256) {
                int col = t >> 2, chunk = t & 3;
                int h = h0 + (col >> 6), d = col & 63;
                unsigned short tmp[16] __attribute__((aligned(16)));
                #pragma unroll
                for (int j = 0; j < 16; ++j) tmp[j] = f2bf(Cs[chunk * 16 + j][col]);
                size_t base = (((size_t)b * Hc + h) * Dc + d) * Sc
                              + sbase + pass * 64 + chunk * 16;
                *(shortx8*)(out + base)     = *(shortx8*)&tmp[0];
                *(shortx8*)(out + base + 8) = *(shortx8*)&tmp[8];
            }
            __syncthreads();
        }
    }
}

// ---------------------------------------------------------------------------
// Kernel 2: MFMA flash attention, v4.
// QTILE=256 per block (4 q-strips per wave): each kf/vf fragment read feeds
// 4 MFMAs (was 2) -> LDS-pipe fragment traffic per CU halves; K/V staging DMA
// and HBM re-fetch halve.  Grid (8,2,32) = 512 blocks = 2/CU;
// __launch_bounds__(256,2) pins 2 waves/SIMD so VGPR can't drop occupancy
// below the grid's own limit.
// P repack is fully in-register (cvt_pk + permlane swaps, VALU pipe):
//   a=pk(p[2ks][0],p[2ks][1]), b=pk(p[2ks+1][0],p[2ks+1][1])
//   swap32(a,b); swap16(a,b)  ->  a = pf.x[0], b = pf.x[2]  (pw pair -> x[1],x[3])
// K/V double-buffered (2x16K), one barrier per K-tile; stage(kt+1) issues
// right after the barrier and flies under compute(kt).
// ---------------------------------------------------------------------------
__global__ __launch_bounds__(256, 2) void attn_mfma_kernel(
    const unsigned short* __restrict__ qg,   // [B,H,S,D]
    const unsigned short* __restrict__ kg,   // [B,H,S,D]
    const unsigned short* __restrict__ vtg,  // [B,H,D,S]
    unsigned short* __restrict__ o1,         // partial O, half 0 [B,S,E]
    unsigned short* __restrict__ o2,         // partial O, half 1 [B,S,E]
    float* __restrict__ lpart)               // [2][B*H][S]
{
    __shared__ __align__(16) char smem[32768];   // buf0: Ks 8K|VTs 8K, buf1: same

    const int tid  = threadIdx.x;
    const int lane = tid & 63;
    const int w    = tid >> 6;
    const int l15  = tid & 15;
    const int quad = (tid >> 4) & 3;
    const int qb   = blockIdx.x;             // 0..7 (256 q-rows per block)
    const int half = blockIdx.y;
    const int bh   = blockIdx.z;
    const int sw   = l15 & 7;

    const unsigned short* qp = qg  + (size_t)bh * Sc * Dc;
    const unsigned short* kp = kg  + (size_t)bh * Sc * Dc;
    const unsigned short* vp = vtg + (size_t)bh * Dc * Sc;

    int qrow[4];
    shortx8 qf[4][2];
    #pragma unroll
    for (int qs = 0; qs < 4; ++qs) {
        qrow[qs] = qb * 256 + 64 * w + 16 * qs + l15;
        qf[qs][0] = *(const shortx8*)(qp + (size_t)qrow[qs] * Dc + 8 * quad);
        qf[qs][1] = *(const shortx8*)(qp + (size_t)qrow[qs] * Dc + 32 + 8 * quad);
    }

    floatx4 Oacc[4][4];
    #pragma unroll
    for (int qs = 0; qs < 4; ++qs)
        #pragma unroll
        for (int mt = 0; mt < 4; ++mt)
            #pragma unroll
            for (int e = 0; e < 4; ++e) Oacc[qs][mt][e] = 0.0f;
    float lsum[4] = {0.0f, 0.0f, 0.0f, 0.0f};

    const float cexp = 0.125f * 1.442695041f;   // score scale * log2(e)

    // async stage of one 64-row K tile + matching V^T tile into buffer `buf`
    auto stage = [&](int kt, int buf) {
        #pragma unroll
        for (int j = 0; j < 2; ++j) {
            int idx = j * 64 + lane;
            int row = 16 * w + (idx >> 3);
            int cg  = ((idx & 7) ^ (idx >> 3)) & 7;
            gll16(kp + (size_t)(kt * 64 + row) * Dc + cg * 8,
                  smem + (buf << 14) + 2048 * w + 1024 * j);
            gll16(vp + (size_t)row * Sc + kt * 64 + cg * 8,
                  smem + (buf << 14) + 8192 + 2048 * w + 1024 * j);
        }
    };

    int cur = 0;
    stage(half * 16, 0);

    for (int it = 0; it < 16; ++it) {
        const int kt = half * 16 + it;
        // barrier drains this thread's vmcnt (stage(kt) landed) and guarantees
        // all waves finished reading buf cur^1 (tile kt-1) -> safe to overwrite.
        __syncthreads();
        if (it < 15) stage(kt + 1, cur ^ 1);

        const char* kb = smem + (cur << 14);

        // fragment loads: 16 ds_read_b128 feeding 128 MFMAs
        shortx8 kf[2][4], vf[2][4];
        #pragma unroll
        for (int ks = 0; ks < 2; ++ks)
            #pragma unroll
            for (int mt = 0; mt < 4; ++mt) {
                int off = (16 * mt + l15) * 128 + (((4 * ks + quad) ^ sw) << 4);
                kf[ks][mt] = *(shortx8*)(kb + off);
                vf[ks][mt] = *(shortx8*)(kb + 8192 + off);
            }

        #pragma unroll
        for (int qs = 0; qs < 4; ++qs) {
            // --- QK^T ---
            floatx4 st[4];
            #pragma unroll
            for (int mt = 0; mt < 4; ++mt)
                #pragma unroll
                for (int e = 0; e < 4; ++e) st[mt][e] = 0.0f;
            #pragma unroll
            for (int ks = 0; ks < 2; ++ks)
                #pragma unroll
                for (int mt = 0; mt < 4; ++mt)
                    st[mt] = __builtin_amdgcn_mfma_f32_16x16x32_bf16(
                        kf[ks][mt], qf[qs][ks], st[mt], 0, 0, 0);

            // --- exp + pack (per-qs locals only) ---
            unsigned pu[4], pw[4];
            float rs = 0.0f;
            #pragma unroll
            for (int mt = 0; mt < 4; ++mt) {
                float p0 = exp2_fast(st[mt][0] * cexp);
                float p1 = exp2_fast(st[mt][1] * cexp);
                float p2 = exp2_fast(st[mt][2] * cexp);
                float p3 = exp2_fast(st[mt][3] * cexp);
                rs += (p0 + p1) + (p2 + p3);
                pu[mt] = cvtpk_bf16(p0, p1);
                pw[mt] = cvtpk_bf16(p2, p3);
            }
            lsum[qs] += rs;

            // --- in-register repack + PV ---
            #pragma unroll
            for (int ks = 0; ks < 2; ++ks) {
                unsigned a = pu[2 * ks], b = pu[2 * ks + 1];
                unsigned c = pw[2 * ks], d = pw[2 * ks + 1];
                swap32(a, b, lane); swap16(a, b, lane);
                swap32(c, d, lane); swap16(c, d, lane);
                union { unsigned x[4]; shortx8 s; } pf;
                pf.x[0] = a; pf.x[1] = c; pf.x[2] = b; pf.x[3] = d;
                #pragma unroll
                for (int mt = 0; mt < 4; ++mt)
                    Oacc[qs][mt] = __builtin_amdgcn_mfma_f32_16x16x32_bf16(
                        vf[ks][mt], pf.s, Oacc[qs][mt], 0, 0, 0);
            }
        }

        cur ^= 1;
    }

    // store partial O (bf16, unnormalized) + partial l (fp32)
    const int b = bh >> 4, hh = bh & 15;
    unsigned short* opart = half ? o2 : o1;
    float* lp = lpart + ((size_t)half * (Bc * Hc) + bh) * Sc;
    #pragma unroll
    for (int qs = 0; qs < 4; ++qs) {
        float l = lsum[qs];
        l += __shfl_xor(l, 16, 64);
        l += __shfl_xor(l, 32, 64);
        if (quad == 0) lp[qrow[qs]] = l;
        #pragma unroll
        for (int mt = 0; mt < 4; ++mt) {
            unsigned short tmp[4] __attribute__((aligned(8)));
            #pragma unroll
            for (int r = 0; r < 4; ++r) tmp[r] = f2bf(Oacc[qs][mt][r]);
            size_t base = ((size_t)b * Sc + qrow[qs]) * Ec + hh * 64 + 16 * mt + 4 * quad;
            *(uint2*)(opart + base) = *(uint2*)tmp;
        }
    }
}

// ---------------------------------------------------------------------------
// Kernel 2b: combine halves: att = (O1 + O2) / (l1 + l2), in place into o1.
// ---------------------------------------------------------------------------
__global__ __launch_bounds__(256) void combine_kernel(
    unsigned short* __restrict__ o1,         // in/out (becomes att)
    const unsigned short* __restrict__ o2,
    const float* __restrict__ lpart)         // [2][B*H][S]
{
    const size_t t = (size_t)blockIdx.x * 256 + threadIdx.x;
    const size_t base = t * 8;
    const int e = (int)(base & (Ec - 1));
    const int h = e >> 6;
    const size_t bs = base >> 10;
    const int b = (int)(bs >> 11), s = (int)(bs & (Sc - 1));
    const int bh = b * Hc + h;
    const float l = lpart[(size_t)bh * Sc + s]
                  + lpart[(size_t)(Bc * Hc + bh) * Sc + s];
    const float inv = 1.0f / l;
    uint4 a = *(const uint4*)(o1 + base);
    uint4 c = *(const uint4*)(o2 + base);
    const unsigned short* ua = (const unsigned short*)&a;
    const unsigned short* uc = (const unsigned short*)&c;
    unsigned short r[8] __attribute__((aligned(16)));
    #pragma unroll
    for (int i = 0; i < 8; ++i)
        r[i] = f2bf((bf2f(ua[i]) + bf2f(uc[i])) * inv);
    *(uint4*)(o1 + base) = *(uint4*)r;
}

// ---------------------------------------------------------------------------
// Kernel 3: MFMA out-projection, 64x128 tile, async swizzled staging.
// ---------------------------------------------------------------------------
__global__ __launch_bounds__(256) void outproj_mfma_kernel(
    const unsigned short* __restrict__ Ab,   // attb [4096,1024]
    const unsigned short* __restrict__ Wb,   // Wcb [1024,1024]
    const float* __restrict__ bias,
    float* __restrict__ out)                 // [4096,1024] fp32
{
    __shared__ __align__(16) char smem[24576];   // As 8K | Ws 16K

    const int tid = threadIdx.x;
    const int lane = tid & 63;
    const int w = tid >> 6, l15 = tid & 15, quad = (tid >> 4) & 3;
    const int wq = w >> 1, wn = w & 1;
    const int m0 = blockIdx.x * 64;
    const int n0 = blockIdx.y * 128;
    const int sw = l15 & 7;

    floatx4 acc[2][4];
    #pragma unroll
    for (int ms = 0; ms < 2; ++ms)
        #pragma unroll
        for (int ns = 0; ns < 4; ++ns)
            #pragma unroll
            for (int e = 0; e < 4; ++e) acc[ms][ns][e] = 0.0f;

    for (int k0 = 0; k0 < Kdim; k0 += 64) {
        #pragma unroll
        for (int j = 0; j < 2; ++j) {
            int idx = j * 64 + lane;
            int row = 16 * w + (idx >> 3);
            int cg  = ((idx & 7) ^ (idx >> 3)) & 7;
            gll16(Ab + (size_t)(m0 + row) * Kdim + k0 + cg * 8,
                  smem + 2048 * w + 1024 * j);
        }
        #pragma unroll
        for (int j = 0; j < 4; ++j) {
            int idx = j * 64 + lane;
            int row = 32 * w + (idx >> 3);
            int cg  = ((idx & 7) ^ (idx >> 3)) & 7;
            gll16(Wb + (size_t)(n0 + row) * Kdim + k0 + cg * 8,
                  smem + 8192 + 4096 * w + 1024 * j);
        }
        __syncthreads();
        #pragma unroll
        for (int ks = 0; ks < 2; ++ks) {
            shortx8 af[2], bf[4];
            #pragma unroll
            for (int ms = 0; ms < 2; ++ms)
                af[ms] = *(shortx8*)(smem + (32 * wq + 16 * ms + l15) * 128
                                     + (((4 * ks + quad) ^ sw) << 4));
            #pragma unroll
            for (int ns = 0; ns < 4; ++ns)
                bf[ns] = *(shortx8*)(smem + 8192 + (64 * wn + 16 * ns + l15) * 128
                                     + (((4 * ks + quad) ^ sw) << 4));
            #pragma unroll
            for (int ms = 0; ms < 2; ++ms)
                #pragma unroll
                for (int ns = 0; ns < 4; ++ns)
                    acc[ms][ns] = __builtin_amdgcn_mfma_f32_16x16x32_bf16(
                        af[ms], bf[ns], acc[ms][ns], 0, 0, 0);
        }
        __syncthreads();
    }

    #pragma unroll
    for (int ns = 0; ns < 4; ++ns) {
        const float bv = bias[n0 + 64 * wn + 16 * ns + l15];
        #pragma unroll
        for (int ms = 0; ms < 2; ++ms)
            #pragma unroll
            for (int r = 0; r < 4; ++r) {
                int m = m0 + 32 * wq + 16 * ms + 4 * quad + r;
                out[(size_t)m * Kdim + n0 + 64 * wn + 16 * ns + l15] = acc[ms][ns][r] + bv;
            }
    }
}

// ---------------------------------------------------------------------------
extern "C" void kernel_launch(void* const* d_in, const int* in_sizes, int n_in,
                              void* d_out, int out_size, void* d_ws, size_t ws_size,
                              hipStream_t stream) {
    const float* x  = (const float*)d_in[0];
    const float* Wq = (const float*)d_in[1];
    const float* Wk = (const float*)d_in[2];
    const float* Wv = (const float*)d_in[3];
    const float* Wc = (const float*)d_in[4];
    const float* bc = (const float*)d_in[5];
    float* out = (float*)d_out;

    // ws layout (48 MB): xb 8M | Wqb/Wkb/Wvb/Wcb 2M ea | qb 8M | kb 8M | vtb 8M
    // | attb 8M.  After proj, xb region is reused as O2 partial and Wqb region
    // as lpart (both dead); attb region doubles as O1 partial (combined in place).
    char* p = (char*)d_ws;
    unsigned short* xb   = (unsigned short*)(p);
    unsigned short* Wqb  = (unsigned short*)(p + (8u << 20));
    unsigned short* Wkb  = (unsigned short*)(p + (10u << 20));
    unsigned short* Wvb  = (unsigned short*)(p + (12u << 20));
    unsigned short* Wcb  = (unsigned short*)(p + (14u << 20));
    unsigned short* qb_  = (unsigned short*)(p + (16u << 20));
    unsigned short* kb_  = (unsigned short*)(p + (24u << 20));
    unsigned short* vtb  = (unsigned short*)(p + (32u << 20));
    unsigned short* attb = (unsigned short*)(p + (40u << 20));
    unsigned short* o2b  = xb;                    // dead after proj
    float*          lpart = (float*)(p + (8u << 20));   // dead Wqb region

    hipLaunchKernelGGL(convert_all_kernel, dim3(8192), dim3(256), 0, stream,
                       x, Wq, Wk, Wv, Wc, xb, Wqb, Wkb, Wvb, Wcb);

    hipLaunchKernelGGL(proj_mfma_kernel, dim3(Mrows / 128, Ec / 128, 3), dim3(256), 0, stream,
                       xb, Wqb, Wkb, Wvb, qb_, kb_, vtb);

    hipLaunchKernelGGL(attn_mfma_kernel, dim3(Sc / 256, 2, Bc * Hc), dim3(256), 0, stream,
                       qb_, kb_, vtb, attb, o2b, lpart);

    hipLaunchKernelGGL(combine_kernel, dim3(Mrows * Ec / (256 * 8)), dim3(256), 0, stream,
                       attb, o2b, lpart);

    hipLaunchKernelGGL(outproj_mfma_kernel, dim3(Mrows / 64, Ec / 128), dim3(256), 0, stream,
                       attb, Wcb, bc, out);
}

// Round 5
// 187.573 us; speedup vs baseline: 1.1296x; 1.0331x over previous
//
#include <hip/hip_runtime.h>
#include <hip/hip_bf16.h>

// Problem constants
constexpr int Bc = 2, Sc = 2048, Ec = 1024, Hc = 16, Dc = 64;
constexpr int Mrows = Bc * Sc;   // 4096
constexpr int Kdim  = Ec;        // 1024

typedef float  floatx4 __attribute__((ext_vector_type(4)));
typedef short  shortx8 __attribute__((ext_vector_type(8)));
typedef unsigned uintx2 __attribute__((ext_vector_type(2)));

__device__ inline unsigned short f2bf(float f) {
    union { __hip_bfloat16 h; unsigned short u; } cv;
    cv.h = __float2bfloat16(f);
    return cv.u;
}
__device__ inline float bf2f(unsigned short u) {
    union { unsigned int i; float f; } c; c.i = ((unsigned int)u) << 16; return c.f;
}
__device__ inline float exp2_fast(float x) {
#if __has_builtin(__builtin_amdgcn_exp2f)
    return __builtin_amdgcn_exp2f(x);
#else
    return __expf(x * 0.69314718056f);
#endif
}

// pack two f32 -> one dword of 2x bf16 (lo->[15:0], hi->[31:16])
// HW-verified gfx950 asm (learn_hip m214v22 / m240 — no builtin exists).
__device__ __forceinline__ unsigned cvtpk_bf16(float lo, float hi) {
    unsigned r;
    asm("v_cvt_pk_bf16_f32 %0, %1, %2" : "=v"(r) : "v"(lo), "v"(hi));
    return r;
}

// Register-pair half-swaps.  Semantics:
//   swap32: a[32:63] <-> b[0:31]
//   swap16: a[16:31]<->b[0:15], a[48:63]<->b[32:47]
// Primary: gfx950 v_permlane{32,16}_swap_b32 via builtin (VALU pipe — keeps
// the repack OFF the LDS pipe).  Fallback: __shfl_xor emulation (ds_bpermute,
// LDS pipe) — identical lane mapping, HW-verified in round 3.
#if __has_builtin(__builtin_amdgcn_permlane32_swap)
__device__ __forceinline__ void swap32(unsigned& a, unsigned& b, int) {
    uintx2 r = __builtin_amdgcn_permlane32_swap(a, b, false, false);
    a = r[0]; b = r[1];
}
#else
__device__ __forceinline__ void swap32(unsigned& a, unsigned& b, int lane) {
    unsigned a2 = __shfl_xor(a, 32, 64);
    unsigned b2 = __shfl_xor(b, 32, 64);
    const bool lo = (lane & 32) == 0;
    unsigned na = lo ? a : b2;
    unsigned nb = lo ? a2 : b;
    a = na; b = nb;
}
#endif
#if __has_builtin(__builtin_amdgcn_permlane16_swap)
__device__ __forceinline__ void swap16(unsigned& a, unsigned& b, int) {
    uintx2 r = __builtin_amdgcn_permlane16_swap(a, b, false, false);
    a = r[0]; b = r[1];
}
#else
__device__ __forceinline__ void swap16(unsigned& a, unsigned& b, int lane) {
    unsigned a2 = __shfl_xor(a, 16, 64);
    unsigned b2 = __shfl_xor(b, 16, 64);
    const bool lo = (lane & 16) == 0;
    unsigned na = lo ? a : b2;
    unsigned nb = lo ? a2 : b;
    a = na; b = nb;
}
#endif

// async global->LDS DMA, 16 B/lane; HW dest = wave-uniform base + lane*16.
__device__ __forceinline__ void gll16(const void* g, void* lds) {
    __builtin_amdgcn_global_load_lds(
        (const __attribute__((address_space(1))) void*)g,
        (__attribute__((address_space(3))) void*)lds, 16, 0, 0);
}

// ---------------------------------------------------------------------------
// Kernel 0: convert x, Wq, Wk, Wv, Wc (fp32) -> bf16 workspace
// ---------------------------------------------------------------------------
__global__ __launch_bounds__(256) void convert_all_kernel(
    const float* __restrict__ x,  const float* __restrict__ Wq,
    const float* __restrict__ Wk, const float* __restrict__ Wv,
    const float* __restrict__ Wc,
    unsigned short* __restrict__ xb,  unsigned short* __restrict__ Wqb,
    unsigned short* __restrict__ Wkb, unsigned short* __restrict__ Wvb,
    unsigned short* __restrict__ Wcb)
{
    const long t = (long)blockIdx.x * 256 + threadIdx.x;
    const long i = t * 4;
    const float* src; unsigned short* dst; long off;
    if (i < 4194304) { src = x; dst = xb; off = i; }
    else {
        long j = i - 4194304;
        int wsel = (int)(j >> 20);
        off = j & 1048575;
        src = (wsel == 0) ? Wq : (wsel == 1) ? Wk : (wsel == 2) ? Wv : Wc;
        dst = (wsel == 0) ? Wqb : (wsel == 1) ? Wkb : (wsel == 2) ? Wvb : Wcb;
    }
    float4 v = *(const float4*)(src + off);
    unsigned short tmp[4] __attribute__((aligned(8)));
    tmp[0] = f2bf(v.x); tmp[1] = f2bf(v.y); tmp[2] = f2bf(v.z); tmp[3] = f2bf(v.w);
    *(uint2*)(dst + off) = *(uint2*)tmp;
}

// ---------------------------------------------------------------------------
// Kernel 1: MFMA projection + quantum epilogue, 128x128 tile.
// v2: K-loop staging is DOUBLE-BUFFERED (2 x 32 KB).  One barrier per K-step;
// stage(k+1) issues right after the barrier and flies under compute(k) —
// removes the single-buffer vmcnt(0) stall (m233 2-phase overhead).
// Tiles are UNPADDED (row stride 128 B); global reads are chunk-swizzled
// (cg = c ^ (row&7)) so b128 fragment reads spread uniformly over banks.
// blockIdx.z selects {q,k,v}; z==2 writes V transposed [B,H,D,S].
// ---------------------------------------------------------------------------
__global__ __launch_bounds__(256) void proj_mfma_kernel(
    const unsigned short* __restrict__ Ab,   // x bf16 [4096,1024]
    const unsigned short* __restrict__ Wqb,
    const unsigned short* __restrict__ Wkb,
    const unsigned short* __restrict__ Wvb,
    unsigned short* __restrict__ oq,         // [B,H,S,D]
    unsigned short* __restrict__ ok,         // [B,H,S,D]
    unsigned short* __restrict__ ov)         // [B,H,D,S]
{
    // staging: buf0 [0,32K) = As 16K | Ws 16K ; buf1 [32K,64K) = same.
    // Epilogue Cs (33792 B) overlays [0,33792) after the K-loop.
    __shared__ __align__(16) char smem[65536];
    float (*Cs)[132] = (float(*)[132])smem;
    __shared__ float Sp[64][9];

    const int z = blockIdx.z;
    const unsigned short* Wb = (z == 0) ? Wqb : (z == 1) ? Wkb : Wvb;
    unsigned short* out      = (z == 0) ? oq  : (z == 1) ? ok  : ov;
    const int mode = (z == 2) ? 1 : 0;

    const int tid = threadIdx.x;
    const int lane = tid & 63;
    const int w = tid >> 6, l15 = tid & 15, quad = (tid >> 4) & 3;
    const int wq = w >> 1, wn = w & 1;
    const int m0 = blockIdx.x * 128;
    const int n0 = blockIdx.y * 128;
    const int h0 = n0 >> 6;
    const int sw = l15 & 7;

    floatx4 acc[4][4];
    #pragma unroll
    for (int ms = 0; ms < 4; ++ms)
        #pragma unroll
        for (int ns = 0; ns < 4; ++ns)
            #pragma unroll
            for (int e = 0; e < 4; ++e) acc[ms][ns][e] = 0.0f;

    // async stage of one K-step (A-tile 16K + W-tile 16K) into buffer `buf`
    auto stage = [&](int k0, int buf) {
        #pragma unroll
        for (int j = 0; j < 4; ++j) {
            int idx = j * 64 + lane;
            int row = 32 * w + (idx >> 3);
            int cg  = ((idx & 7) ^ (idx >> 3)) & 7;
            gll16(Ab + (size_t)(m0 + row) * Kdim + k0 + cg * 8,
                  smem + (buf << 15) + 4096 * w + 1024 * j);
            gll16(Wb + (size_t)(n0 + row) * Kdim + k0 + cg * 8,
                  smem + (buf << 15) + 16384 + 4096 * w + 1024 * j);
        }
    };

    int cur = 0;
    stage(0, 0);

    for (int k0 = 0; k0 < Kdim; k0 += 64) {
        // barrier drains this thread's vmcnt (stage(k0) landed) and guarantees
        // all waves finished reading buf cur^1 -> safe to overwrite.
        __syncthreads();
        if (k0 + 64 < Kdim) stage(k0 + 64, cur ^ 1);

        const char* sb = smem + (cur << 15);
        #pragma unroll
        for (int ks = 0; ks < 2; ++ks) {
            shortx8 af[4], bf[4];
            #pragma unroll
            for (int ms = 0; ms < 4; ++ms)
                af[ms] = *(shortx8*)(sb + (64 * wq + 16 * ms + l15) * 128
                                     + (((4 * ks + quad) ^ sw) << 4));
            #pragma unroll
            for (int ns = 0; ns < 4; ++ns)
                bf[ns] = *(shortx8*)(sb + 16384 + (64 * wn + 16 * ns + l15) * 128
                                     + (((4 * ks + quad) ^ sw) << 4));
            #pragma unroll
            for (int ms = 0; ms < 4; ++ms)
                #pragma unroll
                for (int ns = 0; ns < 4; ++ns)
                    acc[ms][ns] = __builtin_amdgcn_mfma_f32_16x16x32_bf16(
                        af[ms], bf[ns], acc[ms][ns], 0, 0, 0);
        }
        cur ^= 1;
    }
    __syncthreads();   // all waves done reading staging before Cs overlays it

    const int b = m0 >> 11;
    const int sbase = m0 & (Sc - 1);

    // Epilogue: two 64-row passes (Cs overlays staging LDS; K-loop done)
    for (int pass = 0; pass < 2; ++pass) {
        if (wq == pass) {
            #pragma unroll
            for (int ms = 0; ms < 4; ++ms)
                #pragma unroll
                for (int ns = 0; ns < 4; ++ns)
                    #pragma unroll
                    for (int r = 0; r < 4; ++r)
                        Cs[16 * ms + 4 * quad + r][64 * wn + 16 * ns + l15] =
                            __cosf(acc[ms][ns][r]);
        }
        __syncthreads();
        #pragma unroll
        for (int t = tid; t < 512; t += 256) {
            int row = t >> 3, seg = t & 7;
            float pr = 1.0f;
            #pragma unroll
            for (int c = 0; c < 16; ++c) pr *= Cs[row][seg * 16 + c];
            Sp[row][seg] = pr;
        }
        __syncthreads();
        if (mode == 0) {
            #pragma unroll
            for (int t = tid; t < 512; t += 256) {
                int row = t >> 3, seg = t & 7;
                float p = 1.0f;
                for (int j = (seg & 4); j < seg; ++j) p *= Sp[row][j];
                unsigned short tmp[16] __attribute__((aligned(16)));
                #pragma unroll
                for (int c = 0; c < 16; ++c) { p *= Cs[row][seg * 16 + c]; tmp[c] = f2bf(p); }
                int h = h0 + (seg >> 2);
                int s = sbase + pass * 64 + row;
                size_t base = (((size_t)b * Hc + h) * Sc + s) * Dc + (seg & 3) * 16;
                *(shortx8*)(out + base)     = *(shortx8*)&tmp[0];
                *(shortx8*)(out + base + 8) = *(shortx8*)&tmp[8];
            }
            __syncthreads();
        } else {
            #pragma unroll
            for (int t = tid; t < 512; t += 256) {
                int row = t >> 3, seg = t & 7;
                float p = 1.0f;
                for (int j = (seg & 4); j < seg; ++j) p *= Sp[row][j];
                #pragma unroll
                for (int c = 0; c < 16; ++c) { p *= Cs[row][seg * 16 + c]; Cs[row][seg * 16 + c] = p; }
            }
            __syncthreads();
            #pragma unroll
            for (int t = tid; t < 512; t += 256) {
                int col = t >> 2, chunk = t & 3;
                int h = h0 + (col >> 6), d = col & 63;
                unsigned short tmp[16] __attribute__((aligned(16)));
                #pragma unroll
                for (int j = 0; j < 16; ++j) tmp[j] = f2bf(Cs[chunk * 16 + j][col]);
                size_t base = (((size_t)b * Hc + h) * Dc + d) * Sc
                              + sbase + pass * 64 + chunk * 16;
                *(shortx8*)(out + base)     = *(shortx8*)&tmp[0];
                *(shortx8*)(out + base + 8) = *(shortx8*)&tmp[8];
            }
            __syncthreads();
        }
    }
}

// ---------------------------------------------------------------------------
// Kernel 2: MFMA flash attention, v4 (unchanged from round 4).
// QTILE=256 per block (4 q-strips per wave); P repack fully in-register
// (cvt_pk + permlane swaps); K/V double-buffered, one barrier per K-tile.
// ---------------------------------------------------------------------------
__global__ __launch_bounds__(256, 2) void attn_mfma_kernel(
    const unsigned short* __restrict__ qg,   // [B,H,S,D]
    const unsigned short* __restrict__ kg,   // [B,H,S,D]
    const unsigned short* __restrict__ vtg,  // [B,H,D,S]
    unsigned short* __restrict__ o1,         // partial O, half 0 [B,S,E]
    unsigned short* __restrict__ o2,         // partial O, half 1 [B,S,E]
    float* __restrict__ lpart)               // [2][B*H][S]
{
    __shared__ __align__(16) char smem[32768];   // buf0: Ks 8K|VTs 8K, buf1: same

    const int tid  = threadIdx.x;
    const int lane = tid & 63;
    const int w    = tid >> 6;
    const int l15  = tid & 15;
    const int quad = (tid >> 4) & 3;
    const int qb   = blockIdx.x;             // 0..7 (256 q-rows per block)
    const int half = blockIdx.y;
    const int bh   = blockIdx.z;
    const int sw   = l15 & 7;

    const unsigned short* qp = qg  + (size_t)bh * Sc * Dc;
    const unsigned short* kp = kg  + (size_t)bh * Sc * Dc;
    const unsigned short* vp = vtg + (size_t)bh * Dc * Sc;

    int qrow[4];
    shortx8 qf[4][2];
    #pragma unroll
    for (int qs = 0; qs < 4; ++qs) {
        qrow[qs] = qb * 256 + 64 * w + 16 * qs + l15;
        qf[qs][0] = *(const shortx8*)(qp + (size_t)qrow[qs] * Dc + 8 * quad);
        qf[qs][1] = *(const shortx8*)(qp + (size_t)qrow[qs] * Dc + 32 + 8 * quad);
    }

    floatx4 Oacc[4][4];
    #pragma unroll
    for (int qs = 0; qs < 4; ++qs)
        #pragma unroll
        for (int mt = 0; mt < 4; ++mt)
            #pragma unroll
            for (int e = 0; e < 4; ++e) Oacc[qs][mt][e] = 0.0f;
    float lsum[4] = {0.0f, 0.0f, 0.0f, 0.0f};

    const float cexp = 0.125f * 1.442695041f;   // score scale * log2(e)

    // async stage of one 64-row K tile + matching V^T tile into buffer `buf`
    auto stage = [&](int kt, int buf) {
        #pragma unroll
        for (int j = 0; j < 2; ++j) {
            int idx = j * 64 + lane;
            int row = 16 * w + (idx >> 3);
            int cg  = ((idx & 7) ^ (idx >> 3)) & 7;
            gll16(kp + (size_t)(kt * 64 + row) * Dc + cg * 8,
                  smem + (buf << 14) + 2048 * w + 1024 * j);
            gll16(vp + (size_t)row * Sc + kt * 64 + cg * 8,
                  smem + (buf << 14) + 8192 + 2048 * w + 1024 * j);
        }
    };

    int cur = 0;
    stage(half * 16, 0);

    for (int it = 0; it < 16; ++it) {
        const int kt = half * 16 + it;
        // barrier drains this thread's vmcnt (stage(kt) landed) and guarantees
        // all waves finished reading buf cur^1 (tile kt-1) -> safe to overwrite.
        __syncthreads();
        if (it < 15) stage(kt + 1, cur ^ 1);

        const char* kb = smem + (cur << 14);

        // fragment loads: 16 ds_read_b128 feeding 128 MFMAs
        shortx8 kf[2][4], vf[2][4];
        #pragma unroll
        for (int ks = 0; ks < 2; ++ks)
            #pragma unroll
            for (int mt = 0; mt < 4; ++mt) {
                int off = (16 * mt + l15) * 128 + (((4 * ks + quad) ^ sw) << 4);
                kf[ks][mt] = *(shortx8*)(kb + off);
                vf[ks][mt] = *(shortx8*)(kb + 8192 + off);
            }

        #pragma unroll
        for (int qs = 0; qs < 4; ++qs) {
            // --- QK^T ---
            floatx4 st[4];
            #pragma unroll
            for (int mt = 0; mt < 4; ++mt)
                #pragma unroll
                for (int e = 0; e < 4; ++e) st[mt][e] = 0.0f;
            #pragma unroll
            for (int ks = 0; ks < 2; ++ks)
                #pragma unroll
                for (int mt = 0; mt < 4; ++mt)
                    st[mt] = __builtin_amdgcn_mfma_f32_16x16x32_bf16(
                        kf[ks][mt], qf[qs][ks], st[mt], 0, 0, 0);

            // --- exp + pack (per-qs locals only) ---
            unsigned pu[4], pw[4];
            float rs = 0.0f;
            #pragma unroll
            for (int mt = 0; mt < 4; ++mt) {
                float p0 = exp2_fast(st[mt][0] * cexp);
                float p1 = exp2_fast(st[mt][1] * cexp);
                float p2 = exp2_fast(st[mt][2] * cexp);
                float p3 = exp2_fast(st[mt][3] * cexp);
                rs += (p0 + p1) + (p2 + p3);
                pu[mt] = cvtpk_bf16(p0, p1);
                pw[mt] = cvtpk_bf16(p2, p3);
            }
            lsum[qs] += rs;

            // --- in-register repack + PV ---
            #pragma unroll
            for (int ks = 0; ks < 2; ++ks) {
                unsigned a = pu[2 * ks], b = pu[2 * ks + 1];
                unsigned c = pw[2 * ks], d = pw[2 * ks + 1];
                swap32(a, b, lane); swap16(a, b, lane);
                swap32(c, d, lane); swap16(c, d, lane);
                union { unsigned x[4]; shortx8 s; } pf;
                pf.x[0] = a; pf.x[1] = c; pf.x[2] = b; pf.x[3] = d;
                #pragma unroll
                for (int mt = 0; mt < 4; ++mt)
                    Oacc[qs][mt] = __builtin_amdgcn_mfma_f32_16x16x32_bf16(
                        vf[ks][mt], pf.s, Oacc[qs][mt], 0, 0, 0);
            }
        }

        cur ^= 1;
    }

    // store partial O (bf16, unnormalized) + partial l (fp32)
    const int b = bh >> 4, hh = bh & 15;
    unsigned short* opart = half ? o2 : o1;
    float* lp = lpart + ((size_t)half * (Bc * Hc) + bh) * Sc;
    #pragma unroll
    for (int qs = 0; qs < 4; ++qs) {
        float l = lsum[qs];
        l += __shfl_xor(l, 16, 64);
        l += __shfl_xor(l, 32, 64);
        if (quad == 0) lp[qrow[qs]] = l;
        #pragma unroll
        for (int mt = 0; mt < 4; ++mt) {
            unsigned short tmp[4] __attribute__((aligned(8)));
            #pragma unroll
            for (int r = 0; r < 4; ++r) tmp[r] = f2bf(Oacc[qs][mt][r]);
            size_t base = ((size_t)b * Sc + qrow[qs]) * Ec + hh * 64 + 16 * mt + 4 * quad;
            *(uint2*)(opart + base) = *(uint2*)tmp;
        }
    }
}

// ---------------------------------------------------------------------------
// Kernel 2b: combine halves: att = (O1 + O2) / (l1 + l2), in place into o1.
// ---------------------------------------------------------------------------
__global__ __launch_bounds__(256) void combine_kernel(
    unsigned short* __restrict__ o1,         // in/out (becomes att)
    const unsigned short* __restrict__ o2,
    const float* __restrict__ lpart)         // [2][B*H][S]
{
    const size_t t = (size_t)blockIdx.x * 256 + threadIdx.x;
    const size_t base = t * 8;
    const int e = (int)(base & (Ec - 1));
    const int h = e >> 6;
    const size_t bs = base >> 10;
    const int b = (int)(bs >> 11), s = (int)(bs & (Sc - 1));
    const int bh = b * Hc + h;
    const float l = lpart[(size_t)bh * Sc + s]
                  + lpart[(size_t)(Bc * Hc + bh) * Sc + s];
    const float inv = 1.0f / l;
    uint4 a = *(const uint4*)(o1 + base);
    uint4 c = *(const uint4*)(o2 + base);
    const unsigned short* ua = (const unsigned short*)&a;
    const unsigned short* uc = (const unsigned short*)&c;
    unsigned short r[8] __attribute__((aligned(16)));
    #pragma unroll
    for (int i = 0; i < 8; ++i)
        r[i] = f2bf((bf2f(ua[i]) + bf2f(uc[i])) * inv);
    *(uint4*)(o1 + base) = *(uint4*)r;
}

// ---------------------------------------------------------------------------
// Kernel 3: MFMA out-projection, 64x128 tile.
// v2: double-buffered staging (2 x 24 KB), one barrier per K-step.
// ---------------------------------------------------------------------------
__global__ __launch_bounds__(256) void outproj_mfma_kernel(
    const unsigned short* __restrict__ Ab,   // attb [4096,1024]
    const unsigned short* __restrict__ Wb,   // Wcb [1024,1024]
    const float* __restrict__ bias,
    float* __restrict__ out)                 // [4096,1024] fp32
{
    __shared__ __align__(16) char smem[49152];   // buf: As 8K | Ws 16K, x2

    const int tid = threadIdx.x;
    const int lane = tid & 63;
    const int w = tid >> 6, l15 = tid & 15, quad = (tid >> 4) & 3;
    const int wq = w >> 1, wn = w & 1;
    const int m0 = blockIdx.x * 64;
    const int n0 = blockIdx.y * 128;
    const int sw = l15 & 7;

    floatx4 acc[2][4];
    #pragma unroll
    for (int ms = 0; ms < 2; ++ms)
        #pragma unroll
        for (int ns = 0; ns < 4; ++ns)
            #pragma unroll
            for (int e = 0; e < 4; ++e) acc[ms][ns][e] = 0.0f;

    auto stage = [&](int k0, int buf) {
        #pragma unroll
        for (int j = 0; j < 2; ++j) {
            int idx = j * 64 + lane;
            int row = 16 * w + (idx >> 3);
            int cg  = ((idx & 7) ^ (idx >> 3)) & 7;
            gll16(Ab + (size_t)(m0 + row) * Kdim + k0 + cg * 8,
                  smem + buf * 24576 + 2048 * w + 1024 * j);
        }
        #pragma unroll
        for (int j = 0; j < 4; ++j) {
            int idx = j * 64 + lane;
            int row = 32 * w + (idx >> 3);
            int cg  = ((idx & 7) ^ (idx >> 3)) & 7;
            gll16(Wb + (size_t)(n0 + row) * Kdim + k0 + cg * 8,
                  smem + buf * 24576 + 8192 + 4096 * w + 1024 * j);
        }
    };

    int cur = 0;
    stage(0, 0);

    for (int k0 = 0; k0 < Kdim; k0 += 64) {
        __syncthreads();
        if (k0 + 64 < Kdim) stage(k0 + 64, cur ^ 1);

        const char* sb = smem + cur * 24576;
        #pragma unroll
        for (int ks = 0; ks < 2; ++ks) {
            shortx8 af[2], bf[4];
            #pragma unroll
            for (int ms = 0; ms < 2; ++ms)
                af[ms] = *(shortx8*)(sb + (32 * wq + 16 * ms + l15) * 128
                                     + (((4 * ks + quad) ^ sw) << 4));
            #pragma unroll
            for (int ns = 0; ns < 4; ++ns)
                bf[ns] = *(shortx8*)(sb + 8192 + (64 * wn + 16 * ns + l15) * 128
                                     + (((4 * ks + quad) ^ sw) << 4));
            #pragma unroll
            for (int ms = 0; ms < 2; ++ms)
                #pragma unroll
                for (int ns = 0; ns < 4; ++ns)
                    acc[ms][ns] = __builtin_amdgcn_mfma_f32_16x16x32_bf16(
                        af[ms], bf[ns], acc[ms][ns], 0, 0, 0);
        }
        cur ^= 1;
    }

    #pragma unroll
    for (int ns = 0; ns < 4; ++ns) {
        const float bv = bias[n0 + 64 * wn + 16 * ns + l15];
        #pragma unroll
        for (int ms = 0; ms < 2; ++ms)
            #pragma unroll
            for (int r = 0; r < 4; ++r) {
                int m = m0 + 32 * wq + 16 * ms + 4 * quad + r;
                out[(size_t)m * Kdim + n0 + 64 * wn + 16 * ns + l15] = acc[ms][ns][r] + bv;
            }
    }
}

// ---------------------------------------------------------------------------
extern "C" void kernel_launch(void* const* d_in, const int* in_sizes, int n_in,
                              void* d_out, int out_size, void* d_ws, size_t ws_size,
                              hipStream_t stream) {
    const float* x  = (const float*)d_in[0];
    const float* Wq = (const float*)d_in[1];
    const float* Wk = (const float*)d_in[2];
    const float* Wv = (const float*)d_in[3];
    const float* Wc = (const float*)d_in[4];
    const float* bc = (const float*)d_in[5];
    float* out = (float*)d_out;

    // ws layout (48 MB): xb 8M | Wqb/Wkb/Wvb/Wcb 2M ea | qb 8M | kb 8M | vtb 8M
    // | attb 8M.  After proj, xb region is reused as O2 partial and Wqb region
    // as lpart (both dead); attb region doubles as O1 partial (combined in place).
    char* p = (char*)d_ws;
    unsigned short* xb   = (unsigned short*)(p);
    unsigned short* Wqb  = (unsigned short*)(p + (8u << 20));
    unsigned short* Wkb  = (unsigned short*)(p + (10u << 20));
    unsigned short* Wvb  = (unsigned short*)(p + (12u << 20));
    unsigned short* Wcb  = (unsigned short*)(p + (14u << 20));
    unsigned short* qb_  = (unsigned short*)(p + (16u << 20));
    unsigned short* kb_  = (unsigned short*)(p + (24u << 20));
    unsigned short* vtb  = (unsigned short*)(p + (32u << 20));
    unsigned short* attb = (unsigned short*)(p + (40u << 20));
    unsigned short* o2b  = xb;                    // dead after proj
    float*          lpart = (float*)(p + (8u << 20));   // dead Wqb region

    hipLaunchKernelGGL(convert_all_kernel, dim3(8192), dim3(256), 0, stream,
                       x, Wq, Wk, Wv, Wc, xb, Wqb, Wkb, Wvb, Wcb);

    hipLaunchKernelGGL(proj_mfma_kernel, dim3(Mrows / 128, Ec / 128, 3), dim3(256), 0, stream,
                       xb, Wqb, Wkb, Wvb, qb_, kb_, vtb);

    hipLaunchKernelGGL(attn_mfma_kernel, dim3(Sc / 256, 2, Bc * Hc), dim3(256), 0, stream,
                       qb_, kb_, vtb, attb, o2b, lpart);

    hipLaunchKernelGGL(combine_kernel, dim3(Mrows * Ec / (256 * 8)), dim3(256), 0, stream,
                       attb, o2b, lpart);

    hipLaunchKernelGGL(outproj_mfma_kernel, dim3(Mrows / 64, Ec / 128), dim3(256), 0, stream,
                       attb, Wcb, bc, out);
}

// Round 10
// 186.932 us; speedup vs baseline: 1.1334x; 1.0034x over previous
//
#include <hip/hip_runtime.h>
#include <hip/hip_bf16.h>

// Problem constants
constexpr int Bc = 2, Sc = 2048, Ec = 1024, Hc = 16, Dc = 64;
constexpr int Mrows = Bc * Sc;   // 4096
constexpr int Kdim  = Ec;        // 1024

typedef float  floatx4 __attribute__((ext_vector_type(4)));
typedef short  shortx8 __attribute__((ext_vector_type(8)));
typedef unsigned uintx2 __attribute__((ext_vector_type(2)));

__device__ inline unsigned short f2bf(float f) {
    union { __hip_bfloat16 h; unsigned short u; } cv;
    cv.h = __float2bfloat16(f);
    return cv.u;
}
__device__ inline float bf2f(unsigned short u) {
    union { unsigned int i; float f; } c; c.i = ((unsigned int)u) << 16; return c.f;
}
__device__ inline float exp2_fast(float x) {
#if __has_builtin(__builtin_amdgcn_exp2f)
    return __builtin_amdgcn_exp2f(x);
#else
    return __expf(x * 0.69314718056f);
#endif
}

// pack two f32 -> one dword of 2x bf16 (lo->[15:0], hi->[31:16])
// HW-verified gfx950 asm (learn_hip m214v22 / m240 — no builtin exists).
__device__ __forceinline__ unsigned cvtpk_bf16(float lo, float hi) {
    unsigned r;
    asm("v_cvt_pk_bf16_f32 %0, %1, %2" : "=v"(r) : "v"(lo), "v"(hi));
    return r;
}

// Register-pair half-swaps.  Semantics:
//   swap32: a[32:63] <-> b[0:31]
//   swap16: a[16:31]<->b[0:15], a[48:63]<->b[32:47]
// Primary: gfx950 v_permlane{32,16}_swap_b32 via builtin (VALU pipe — keeps
// the repack OFF the LDS pipe).  Fallback: __shfl_xor emulation (ds_bpermute,
// LDS pipe) — identical lane mapping, HW-verified in round 3.
#if __has_builtin(__builtin_amdgcn_permlane32_swap)
__device__ __forceinline__ void swap32(unsigned& a, unsigned& b, int) {
    uintx2 r = __builtin_amdgcn_permlane32_swap(a, b, false, false);
    a = r[0]; b = r[1];
}
#else
__device__ __forceinline__ void swap32(unsigned& a, unsigned& b, int lane) {
    unsigned a2 = __shfl_xor(a, 32, 64);
    unsigned b2 = __shfl_xor(b, 32, 64);
    const bool lo = (lane & 32) == 0;
    unsigned na = lo ? a : b2;
    unsigned nb = lo ? a2 : b;
    a = na; b = nb;
}
#endif
#if __has_builtin(__builtin_amdgcn_permlane16_swap)
__device__ __forceinline__ void swap16(unsigned& a, unsigned& b, int) {
    uintx2 r = __builtin_amdgcn_permlane16_swap(a, b, false, false);
    a = r[0]; b = r[1];
}
#else
__device__ __forceinline__ void swap16(unsigned& a, unsigned& b, int lane) {
    unsigned a2 = __shfl_xor(a, 16, 64);
    unsigned b2 = __shfl_xor(b, 16, 64);
    const bool lo = (lane & 16) == 0;
    unsigned na = lo ? a : b2;
    unsigned nb = lo ? a2 : b;
    a = na; b = nb;
}
#endif

// async global->LDS DMA, 16 B/lane; HW dest = wave-uniform base + lane*16.
__device__ __forceinline__ void gll16(const void* g, void* lds) {
    __builtin_amdgcn_global_load_lds(
        (const __attribute__((address_space(1))) void*)g,
        (__attribute__((address_space(3))) void*)lds, 16, 0, 0);
}

// ---------------------------------------------------------------------------
// Kernel 0: convert x, Wq, Wk, Wv, Wc (fp32) -> bf16 workspace
// ---------------------------------------------------------------------------
__global__ __launch_bounds__(256) void convert_all_kernel(
    const float* __restrict__ x,  const float* __restrict__ Wq,
    const float* __restrict__ Wk, const float* __restrict__ Wv,
    const float* __restrict__ Wc,
    unsigned short* __restrict__ xb,  unsigned short* __restrict__ Wqb,
    unsigned short* __restrict__ Wkb, unsigned short* __restrict__ Wvb,
    unsigned short* __restrict__ Wcb)
{
    const long t = (long)blockIdx.x * 256 + threadIdx.x;
    const long i = t * 4;
    const float* src; unsigned short* dst; long off;
    if (i < 4194304) { src = x; dst = xb; off = i; }
    else {
        long j = i - 4194304;
        int wsel = (int)(j >> 20);
        off = j & 1048575;
        src = (wsel == 0) ? Wq : (wsel == 1) ? Wk : (wsel == 2) ? Wv : Wc;
        dst = (wsel == 0) ? Wqb : (wsel == 1) ? Wkb : (wsel == 2) ? Wvb : Wcb;
    }
    float4 v = *(const float4*)(src + off);
    unsigned short tmp[4] __attribute__((aligned(8)));
    tmp[0] = f2bf(v.x); tmp[1] = f2bf(v.y); tmp[2] = f2bf(v.z); tmp[3] = f2bf(v.w);
    *(uint2*)(dst + off) = *(uint2*)tmp;
}

// ---------------------------------------------------------------------------
// Kernel 1: MFMA projection + quantum epilogue, 128x128 tile.
// v2: K-loop staging is DOUBLE-BUFFERED (2 x 32 KB).  One barrier per K-step;
// stage(k+1) issues right after the barrier and flies under compute(k) —
// removes the single-buffer vmcnt(0) stall (m233 2-phase overhead).
// Tiles are UNPADDED (row stride 128 B); global reads are chunk-swizzled
// (cg = c ^ (row&7)) so b128 fragment reads spread uniformly over banks.
// blockIdx.z selects {q,k,v}; z==2 writes V transposed [B,H,D,S].
// ---------------------------------------------------------------------------
__global__ __launch_bounds__(256) void proj_mfma_kernel(
    const unsigned short* __restrict__ Ab,   // x bf16 [4096,1024]
    const unsigned short* __restrict__ Wqb,
    const unsigned short* __restrict__ Wkb,
    const unsigned short* __restrict__ Wvb,
    unsigned short* __restrict__ oq,         // [B,H,S,D]
    unsigned short* __restrict__ ok,         // [B,H,S,D]
    unsigned short* __restrict__ ov)         // [B,H,D,S]
{
    // staging: buf0 [0,32K) = As 16K | Ws 16K ; buf1 [32K,64K) = same.
    // Epilogue Cs (33792 B) overlays [0,33792) after the K-loop.
    __shared__ __align__(16) char smem[65536];
    float (*Cs)[132] = (float(*)[132])smem;
    __shared__ float Sp[64][9];

    const int z = blockIdx.z;
    const unsigned short* Wb = (z == 0) ? Wqb : (z == 1) ? Wkb : Wvb;
    unsigned short* out      = (z == 0) ? oq  : (z == 1) ? ok  : ov;
    const int mode = (z == 2) ? 1 : 0;

    const int tid = threadIdx.x;
    const int lane = tid & 63;
    const int w = tid >> 6, l15 = tid & 15, quad = (tid >> 4) & 3;
    const int wq = w >> 1, wn = w & 1;
    const int m0 = blockIdx.x * 128;
    const int n0 = blockIdx.y * 128;
    const int h0 = n0 >> 6;
    const int sw = l15 & 7;

    floatx4 acc[4][4];
    #pragma unroll
    for (int ms = 0; ms < 4; ++ms)
        #pragma unroll
        for (int ns = 0; ns < 4; ++ns)
            #pragma unroll
            for (int e = 0; e < 4; ++e) acc[ms][ns][e] = 0.0f;

    // async stage of one K-step (A-tile 16K + W-tile 16K) into buffer `buf`
    auto stage = [&](int k0, int buf) {
        #pragma unroll
        for (int j = 0; j < 4; ++j) {
            int idx = j * 64 + lane;
            int row = 32 * w + (idx >> 3);
            int cg  = ((idx & 7) ^ (idx >> 3)) & 7;
            gll16(Ab + (size_t)(m0 + row) * Kdim + k0 + cg * 8,
                  smem + (buf << 15) + 4096 * w + 1024 * j);
            gll16(Wb + (size_t)(n0 + row) * Kdim + k0 + cg * 8,
                  smem + (buf << 15) + 16384 + 4096 * w + 1024 * j);
        }
    };

    int cur = 0;
    stage(0, 0);

    for (int k0 = 0; k0 < Kdim; k0 += 64) {
        // barrier drains this thread's vmcnt (stage(k0) landed) and guarantees
        // all waves finished reading buf cur^1 -> safe to overwrite.
        __syncthreads();
        if (k0 + 64 < Kdim) stage(k0 + 64, cur ^ 1);

        const char* sb = smem + (cur << 15);
        #pragma unroll
        for (int ks = 0; ks < 2; ++ks) {
            shortx8 af[4], bf[4];
            #pragma unroll
            for (int ms = 0; ms < 4; ++ms)
                af[ms] = *(shortx8*)(sb + (64 * wq + 16 * ms + l15) * 128
                                     + (((4 * ks + quad) ^ sw) << 4));
            #pragma unroll
            for (int ns = 0; ns < 4; ++ns)
                bf[ns] = *(shortx8*)(sb + 16384 + (64 * wn + 16 * ns + l15) * 128
                                     + (((4 * ks + quad) ^ sw) << 4));
            #pragma unroll
            for (int ms = 0; ms < 4; ++ms)
                #pragma unroll
                for (int ns = 0; ns < 4; ++ns)
                    acc[ms][ns] = __builtin_amdgcn_mfma_f32_16x16x32_bf16(
                        af[ms], bf[ns], acc[ms][ns], 0, 0, 0);
        }
        cur ^= 1;
    }
    __syncthreads();   // all waves done reading staging before Cs overlays it

    const int b = m0 >> 11;
    const int sbase = m0 & (Sc - 1);

    // Epilogue: two 64-row passes (Cs overlays staging LDS; K-loop done)
    for (int pass = 0; pass < 2; ++pass) {
        if (wq == pass) {
            #pragma unroll
            for (int ms = 0; ms < 4; ++ms)
                #pragma unroll
                for (int ns = 0; ns < 4; ++ns)
                    #pragma unroll
                    for (int r = 0; r < 4; ++r)
                        Cs[16 * ms + 4 * quad + r][64 * wn + 16 * ns + l15] =
                            __cosf(acc[ms][ns][r]);
        }
        __syncthreads();
        #pragma unroll
        for (int t = tid; t < 512; t += 256) {
            int row = t >> 3, seg = t & 7;
            float pr = 1.0f;
            #pragma unroll
            for (int c = 0; c < 16; ++c) pr *= Cs[row][seg * 16 + c];
            Sp[row][seg] = pr;
        }
        __syncthreads();
        if (mode == 0) {
            #pragma unroll
            for (int t = tid; t < 512; t += 256) {
                int row = t >> 3, seg = t & 7;
                float p = 1.0f;
                for (int j = (seg & 4); j < seg; ++j) p *= Sp[row][j];
                unsigned short tmp[16] __attribute__((aligned(16)));
                #pragma unroll
                for (int c = 0; c < 16; ++c) { p *= Cs[row][seg * 16 + c]; tmp[c] = f2bf(p); }
                int h = h0 + (seg >> 2);
                int s = sbase + pass * 64 + row;
                size_t base = (((size_t)b * Hc + h) * Sc + s) * Dc + (seg & 3) * 16;
                *(shortx8*)(out + base)     = *(shortx8*)&tmp[0];
                *(shortx8*)(out + base + 8) = *(shortx8*)&tmp[8];
            }
            __syncthreads();
        } else {
            #pragma unroll
            for (int t = tid; t < 512; t += 256) {
                int row = t >> 3, seg = t & 7;
                float p = 1.0f;
                for (int j = (seg & 4); j < seg; ++j) p *= Sp[row][j];
                #pragma unroll
                for (int c = 0; c < 16; ++c) { p *= Cs[row][seg * 16 + c]; Cs[row][seg * 16 + c] = p; }
            }
            __syncthreads();
            #pragma unroll
            for (int t = tid; t < 512; t += 256) {
                int col = t >> 2, chunk = t & 3;
                int h = h0 + (col >> 6), d = col & 63;
                unsigned short tmp[16] __attribute__((aligned(16)));
                #pragma unroll
                for (int j = 0; j < 16; ++j) tmp[j] = f2bf(Cs[chunk * 16 + j][col]);
                size_t base = (((size_t)b * Hc + h) * Dc + d) * Sc
                              + sbase + pass * 64 + chunk * 16;
                *(shortx8*)(out + base)     = *(shortx8*)&tmp[0];
                *(shortx8*)(out + base + 8) = *(shortx8*)&tmp[8];
            }
            __syncthreads();
        }
    }
}

// ---------------------------------------------------------------------------
// Kernel 2: MFMA flash attention, v4 (the twice-verified configuration).
// QTILE=256 per block (4 q-strips per wave); P repack fully in-register
// (cvt_pk + permlane swaps); K/V double-buffered, one barrier per K-tile.
// ---------------------------------------------------------------------------
__global__ __launch_bounds__(256, 2) void attn_mfma_kernel(
    const unsigned short* __restrict__ qg,   // [B,H,S,D]
    const unsigned short* __restrict__ kg,   // [B,H,S,D]
    const unsigned short* __restrict__ vtg,  // [B,H,D,S]
    unsigned short* __restrict__ o1,         // partial O, half 0 [B,S,E]
    unsigned short* __restrict__ o2,         // partial O, half 1 [B,S,E]
    float* __restrict__ lpart)               // [2][B*H][S]
{
    __shared__ __align__(16) char smem[32768];   // buf0: Ks 8K|VTs 8K, buf1: same

    const int tid  = threadIdx.x;
    const int lane = tid & 63;
    const int w    = tid >> 6;
    const int l15  = tid & 15;
    const int quad = (tid >> 4) & 3;
    const int qb   = blockIdx.x;             // 0..7 (256 q-rows per block)
    const int half = blockIdx.y;
    const int bh   = blockIdx.z;
    const int sw   = l15 & 7;

    const unsigned short* qp = qg  + (size_t)bh * Sc * Dc;
    const unsigned short* kp = kg  + (size_t)bh * Sc * Dc;
    const unsigned short* vp = vtg + (size_t)bh * Dc * Sc;

    int qrow[4];
    shortx8 qf[4][2];
    #pragma unroll
    for (int qs = 0; qs < 4; ++qs) {
        qrow[qs] = qb * 256 + 64 * w + 16 * qs + l15;
        qf[qs][0] = *(const shortx8*)(qp + (size_t)qrow[qs] * Dc + 8 * quad);
        qf[qs][1] = *(const shortx8*)(qp + (size_t)qrow[qs] * Dc + 32 + 8 * quad);
    }

    floatx4 Oacc[4][4];
    #pragma unroll
    for (int qs = 0; qs < 4; ++qs)
        #pragma unroll
        for (int mt = 0; mt < 4; ++mt)
            #pragma unroll
            for (int e = 0; e < 4; ++e) Oacc[qs][mt][e] = 0.0f;
    float lsum[4] = {0.0f, 0.0f, 0.0f, 0.0f};

    const float cexp = 0.125f * 1.442695041f;   // score scale * log2(e)

    // async stage of one 64-row K tile + matching V^T tile into buffer `buf`
    auto stage = [&](int kt, int buf) {
        #pragma unroll
        for (int j = 0; j < 2; ++j) {
            int idx = j * 64 + lane;
            int row = 16 * w + (idx >> 3);
            int cg  = ((idx & 7) ^ (idx >> 3)) & 7;
            gll16(kp + (size_t)(kt * 64 + row) * Dc + cg * 8,
                  smem + (buf << 14) + 2048 * w + 1024 * j);
            gll16(vp + (size_t)row * Sc + kt * 64 + cg * 8,
                  smem + (buf << 14) + 8192 + 2048 * w + 1024 * j);
        }
    };

    int cur = 0;
    stage(half * 16, 0);

    for (int it = 0; it < 16; ++it) {
        const int kt = half * 16 + it;
        // barrier drains this thread's vmcnt (stage(kt) landed) and guarantees
        // all waves finished reading buf cur^1 (tile kt-1) -> safe to overwrite.
        __syncthreads();
        if (it < 15) stage(kt + 1, cur ^ 1);

        const char* kb = smem + (cur << 14);

        // fragment loads: 16 ds_read_b128 feeding 128 MFMAs
        shortx8 kf[2][4], vf[2][4];
        #pragma unroll
        for (int ks = 0; ks < 2; ++ks)
            #pragma unroll
            for (int mt = 0; mt < 4; ++mt) {
                int off = (16 * mt + l15) * 128 + (((4 * ks + quad) ^ sw) << 4);
                kf[ks][mt] = *(shortx8*)(kb + off);
                vf[ks][mt] = *(shortx8*)(kb + 8192 + off);
            }

        #pragma unroll
        for (int qs = 0; qs < 4; ++qs) {
            // --- QK^T ---
            floatx4 st[4];
            #pragma unroll
            for (int mt = 0; mt < 4; ++mt)
                #pragma unroll
                for (int e = 0; e < 4; ++e) st[mt][e] = 0.0f;
            #pragma unroll
            for (int ks = 0; ks < 2; ++ks)
                #pragma unroll
                for (int mt = 0; mt < 4; ++mt)
                    st[mt] = __builtin_amdgcn_mfma_f32_16x16x32_bf16(
                        kf[ks][mt], qf[qs][ks], st[mt], 0, 0, 0);

            // --- exp + pack (per-qs locals only) ---
            unsigned pu[4], pw[4];
            float rs = 0.0f;
            #pragma unroll
            for (int mt = 0; mt < 4; ++mt) {
                float p0 = exp2_fast(st[mt][0] * cexp);
                float p1 = exp2_fast(st[mt][1] * cexp);
                float p2 = exp2_fast(st[mt][2] * cexp);
                float p3 = exp2_fast(st[mt][3] * cexp);
                rs += (p0 + p1) + (p2 + p3);
                pu[mt] = cvtpk_bf16(p0, p1);
                pw[mt] = cvtpk_bf16(p2, p3);
            }
            lsum[qs] += rs;

            // --- in-register repack + PV ---
            #pragma unroll
            for (int ks = 0; ks < 2; ++ks) {
                unsigned a = pu[2 * ks], b = pu[2 * ks + 1];
                unsigned c = pw[2 * ks], d = pw[2 * ks + 1];
                swap32(a, b, lane); swap16(a, b, lane);
                swap32(c, d, lane); swap16(c, d, lane);
                union { unsigned x[4]; shortx8 s; } pf;
                pf.x[0] = a; pf.x[1] = c; pf.x[2] = b; pf.x[3] = d;
                #pragma unroll
                for (int mt = 0; mt < 4; ++mt)
                    Oacc[qs][mt] = __builtin_amdgcn_mfma_f32_16x16x32_bf16(
                        vf[ks][mt], pf.s, Oacc[qs][mt], 0, 0, 0);
            }
        }

        cur ^= 1;
    }

    // store partial O (bf16, unnormalized) + partial l (fp32)
    const int b = bh >> 4, hh = bh & 15;
    unsigned short* opart = half ? o2 : o1;
    float* lp = lpart + ((size_t)half * (Bc * Hc) + bh) * Sc;
    #pragma unroll
    for (int qs = 0; qs < 4; ++qs) {
        float l = lsum[qs];
        l += __shfl_xor(l, 16, 64);
        l += __shfl_xor(l, 32, 64);
        if (quad == 0) lp[qrow[qs]] = l;
        #pragma unroll
        for (int mt = 0; mt < 4; ++mt) {
            unsigned short tmp[4] __attribute__((aligned(8)));
            #pragma unroll
            for (int r = 0; r < 4; ++r) tmp[r] = f2bf(Oacc[qs][mt][r]);
            size_t base = ((size_t)b * Sc + qrow[qs]) * Ec + hh * 64 + 16 * mt + 4 * quad;
            *(uint2*)(opart + base) = *(uint2*)tmp;
        }
    }
}

// ---------------------------------------------------------------------------
// Kernel 2b: combine halves: att = (O1 + O2) / (l1 + l2), in place into o1.
// ---------------------------------------------------------------------------
__global__ __launch_bounds__(256) void combine_kernel(
    unsigned short* __restrict__ o1,         // in/out (becomes att)
    const unsigned short* __restrict__ o2,
    const float* __restrict__ lpart)         // [2][B*H][S]
{
    const size_t t = (size_t)blockIdx.x * 256 + threadIdx.x;
    const size_t base = t * 8;
    const int e = (int)(base & (Ec - 1));
    const int h = e >> 6;
    const size_t bs = base >> 10;
    const int b = (int)(bs >> 11), s = (int)(bs & (Sc - 1));
    const int bh = b * Hc + h;
    const float l = lpart[(size_t)bh * Sc + s]
                  + lpart[(size_t)(Bc * Hc + bh) * Sc + s];
    const float inv = 1.0f / l;
    uint4 a = *(const uint4*)(o1 + base);
    uint4 c = *(const uint4*)(o2 + base);
    const unsigned short* ua = (const unsigned short*)&a;
    const unsigned short* uc = (const unsigned short*)&c;
    unsigned short r[8] __attribute__((aligned(16)));
    #pragma unroll
    for (int i = 0; i < 8; ++i)
        r[i] = f2bf((bf2f(ua[i]) + bf2f(uc[i])) * inv);
    *(uint4*)(o1 + base) = *(uint4*)r;
}

// ---------------------------------------------------------------------------
// Kernel 3: MFMA out-projection, 64x128 tile.
// v2: double-buffered staging (2 x 24 KB), one barrier per K-step.
// ---------------------------------------------------------------------------
__global__ __launch_bounds__(256) void outproj_mfma_kernel(
    const unsigned short* __restrict__ Ab,   // attb [4096,1024]
    const unsigned short* __restrict__ Wb,   // Wcb [1024,1024]
    const float* __restrict__ bias,
    float* __restrict__ out)                 // [4096,1024] fp32
{
    __shared__ __align__(16) char smem[49152];   // buf: As 8K | Ws 16K, x2

    const int tid = threadIdx.x;
    const int lane = tid & 63;
    const int w = tid >> 6, l15 = tid & 15, quad = (tid >> 4) & 3;
    const int wq = w >> 1, wn = w & 1;
    const int m0 = blockIdx.x * 64;
    const int n0 = blockIdx.y * 128;
    const int sw = l15 & 7;

    floatx4 acc[2][4];
    #pragma unroll
    for (int ms = 0; ms < 2; ++ms)
        #pragma unroll
        for (int ns = 0; ns < 4; ++ns)
            #pragma unroll
            for (int e = 0; e < 4; ++e) acc[ms][ns][e] = 0.0f;

    auto stage = [&](int k0, int buf) {
        #pragma unroll
        for (int j = 0; j < 2; ++j) {
            int idx = j * 64 + lane;
            int row = 16 * w + (idx >> 3);
            int cg  = ((idx & 7) ^ (idx >> 3)) & 7;
            gll16(Ab + (size_t)(m0 + row) * Kdim + k0 + cg * 8,
                  smem + buf * 24576 + 2048 * w + 1024 * j);
        }
        #pragma unroll
        for (int j = 0; j < 4; ++j) {
            int idx = j * 64 + lane;
            int row = 32 * w + (idx >> 3);
            int cg  = ((idx & 7) ^ (idx >> 3)) & 7;
            gll16(Wb + (size_t)(n0 + row) * Kdim + k0 + cg * 8,
                  smem + buf * 24576 + 8192 + 4096 * w + 1024 * j);
        }
    };

    int cur = 0;
    stage(0, 0);

    for (int k0 = 0; k0 < Kdim; k0 += 64) {
        __syncthreads();
        if (k0 + 64 < Kdim) stage(k0 + 64, cur ^ 1);

        const char* sb = smem + cur * 24576;
        #pragma unroll
        for (int ks = 0; ks < 2; ++ks) {
            shortx8 af[2], bf[4];
            #pragma unroll
            for (int ms = 0; ms < 2; ++ms)
                af[ms] = *(shortx8*)(sb + (32 * wq + 16 * ms + l15) * 128
                                     + (((4 * ks + quad) ^ sw) << 4));
            #pragma unroll
            for (int ns = 0; ns < 4; ++ns)
                bf[ns] = *(shortx8*)(sb + 8192 + (64 * wn + 16 * ns + l15) * 128
                                     + (((4 * ks + quad) ^ sw) << 4));
            #pragma unroll
            for (int ms = 0; ms < 2; ++ms)
                #pragma unroll
                for (int ns = 0; ns < 4; ++ns)
                    acc[ms][ns] = __builtin_amdgcn_mfma_f32_16x16x32_bf16(
                        af[ms], bf[ns], acc[ms][ns], 0, 0, 0);
        }
        cur ^= 1;
    }

    #pragma unroll
    for (int ns = 0; ns < 4; ++ns) {
        const float bv = bias[n0 + 64 * wn + 16 * ns + l15];
        #pragma unroll
        for (int ms = 0; ms < 2; ++ms)
            #pragma unroll
            for (int r = 0; r < 4; ++r) {
                int m = m0 + 32 * wq + 16 * ms + 4 * quad + r;
                out[(size_t)m * Kdim + n0 + 64 * wn + 16 * ns + l15] = acc[ms][ns][r] + bv;
            }
    }
}

// ---------------------------------------------------------------------------
extern "C" void kernel_launch(void* const* d_in, const int* in_sizes, int n_in,
                              void* d_out, int out_size, void* d_ws, size_t ws_size,
                              hipStream_t stream) {
    const float* x  = (const float*)d_in[0];
    const float* Wq = (const float*)d_in[1];
    const float* Wk = (const float*)d_in[2];
    const float* Wv = (const float*)d_in[3];
    const float* Wc = (const float*)d_in[4];
    const float* bc = (const float*)d_in[5];
    float* out = (float*)d_out;

    // ws layout (48 MB): xb 8M | Wqb/Wkb/Wvb/Wcb 2M ea | qb 8M | kb 8M | vtb 8M
    // | attb 8M.  After proj, xb region is reused as O2 partial and Wqb region
    // as lpart (both dead); attb region doubles as O1 partial (combined in place).
    char* p = (char*)d_ws;
    unsigned short* xb   = (unsigned short*)(p);
    unsigned short* Wqb  = (unsigned short*)(p + (8u << 20));
    unsigned short* Wkb  = (unsigned short*)(p + (10u << 20));
    unsigned short* Wvb  = (unsigned short*)(p + (12u << 20));
    unsigned short* Wcb  = (unsigned short*)(p + (14u << 20));
    unsigned short* qb_  = (unsigned short*)(p + (16u << 20));
    unsigned short* kb_  = (unsigned short*)(p + (24u << 20));
    unsigned short* vtb  = (unsigned short*)(p + (32u << 20));
    unsigned short* attb = (unsigned short*)(p + (40u << 20));
    unsigned short* o2b  = xb;                    // dead after proj
    float*          lpart = (float*)(p + (8u << 20));   // dead Wqb region

    hipLaunchKernelGGL(convert_all_kernel, dim3(8192), dim3(256), 0, stream,
                       x, Wq, Wk, Wv, Wc, xb, Wqb, Wkb, Wvb, Wcb);

    hipLaunchKernelGGL(proj_mfma_kernel, dim3(Mrows / 128, Ec / 128, 3), dim3(256), 0, stream,
                       xb, Wqb, Wkb, Wvb, qb_, kb_, vtb);

    hipLaunchKernelGGL(attn_mfma_kernel, dim3(Sc / 256, 2, Bc * Hc), dim3(256), 0, stream,
                       qb_, kb_, vtb, attb, o2b, lpart);

    hipLaunchKernelGGL(combine_kernel, dim3(Mrows * Ec / (256 * 8)), dim3(256), 0, stream,
                       attb, o2b, lpart);

    hipLaunchKernelGGL(outproj_mfma_kernel, dim3(Mrows / 64, Ec / 128), dim3(256), 0, stream,
                       attb, Wcb, bc, out);
}